// Round 5
// baseline (165.147 us; speedup 1.0000x reference)
//
#include <hip/hip_runtime.h>
#include <float.h>

#define BB 2
#define CC 32
#define HH 96
#define WW 128
#define HW (HH*WW)           // 12288
#define BC (BB*CC)           // 64
#define NPLANE (BC*HW)       // 786432
#define EPSF 1e-6f
#define LOG2E 1.4426950408889634f

// ---- workspace layout (float offsets) ----
#define QR_OFF 0                               // [B*C][H] query row sums
#define QC_OFF (QR_OFF + BC*HH)                // [B*C][W] query col sums
#define QS_OFF (QC_OFF + BC*WW)                // [B*C]    query totals
#define KR_OFF (QS_OFF + BC)                   // [B*C][H] key row sums
#define KC_OFF (KR_OFF + BC*HH)                // [B*C][W] key col sums
#define KS_OFF (KC_OFF + BC*WW)                // [B*C]    key totals
// per-(c0,plane) packed record (vb = c0*BC + plane), RECSZ floats:
//   [0:192)    m pairs   [h][2] = (m_r, m_c), PRE-MULTIPLIED by log2e
//   [192:448)  n pairs   [w][2] = (n_r, n_c)
//   [448:832)  R4        [h][4] 1/rowsum per term
//   [832:1344) C4        [w][4] 1/colsum per term
#define REC_OFF (KS_OFF + BC)                  // == 28800
#define RECSZ 1344
#define MX_OFF (REC_OFF + CC*BC*RECSZ)         // [C0][4] rcmax (atomicMax bits)
#define SMX_OFF (MX_OFF + CC*4)                // [C0]    smax
#define PZ_OFF (SMX_OFF + CC)                  // [B*C0-plane][HW] partial z (group 1)
// total = PZ_OFF + NPLANE = 3567904 floats = 14.27 MB

__device__ __forceinline__ float rcpf(float x) { return __builtin_amdgcn_rcpf(x); }
__device__ __forceinline__ float e2(float x) { return __builtin_amdgcn_exp2f(x); }

// block-wide max, 256 threads = 4 waves of 64
__device__ __forceinline__ float blkmax4(float v) {
  __shared__ float sred[4];
  #pragma unroll
  for (int o = 32; o > 0; o >>= 1) v = fmaxf(v, __shfl_xor(v, o, 64));
  if ((threadIdx.x & 63) == 0) sred[threadIdx.x >> 6] = v;
  __syncthreads();
  float r = fmaxf(fmaxf(sred[0], sred[1]), fmaxf(sred[2], sred[3]));
  __syncthreads();
  return r;
}

// ---------------- K1: per-plane row/col/total sums (queries and keys) ----------------
__global__ __launch_bounds__(256) void k1_plane_sums(const float* __restrict__ q,
                                                     const float* __restrict__ k,
                                                     float* __restrict__ ws) {
  int pb = blockIdx.x;                 // [0, 2*BC): first BC = queries, rest = keys
  int plane = pb & (BC - 1);
  const float* src = (pb < BC ? q : k) + (size_t)plane * HW;
  float* rowO = ws + (pb < BC ? QR_OFF : KR_OFF) + plane * HH;
  float* colO = ws + (pb < BC ? QC_OFF : KC_OFF) + plane * WW;
  float* totO = ws + (pb < BC ? QS_OFF : KS_OFF) + plane;
  __shared__ float cp[4 * WW];
  __shared__ float rsh[HH];
  __shared__ float wtot[2];
  int tid = threadIdx.x;
  int u = tid >> 6, l = tid & 63;
  float csum0 = 0.f, csum1 = 0.f;
  #pragma unroll 4
  for (int r = 0; r < 24; ++r) {
    int h = u * 24 + r;
    float v0 = src[h * WW + l];
    float v1 = src[h * WW + l + 64];
    csum0 += v0; csum1 += v1;
    float rs = v0 + v1;
    #pragma unroll
    for (int o = 1; o < 64; o <<= 1) rs += __shfl_xor(rs, o, 64);
    if (l == 0) { rowO[h] = rs; rsh[h] = rs; }
  }
  cp[u * WW + l] = csum0;
  cp[u * WW + l + 64] = csum1;
  __syncthreads();
  if (tid < WW) colO[tid] = cp[tid] + cp[WW + tid] + cp[2 * WW + tid] + cp[3 * WW + tid];
  float tv = (tid < HH) ? rsh[tid] : 0.f;
  if (tid < 128) {
    #pragma unroll
    for (int o = 1; o < 64; o <<= 1) tv += __shfl_xor(tv, o, 64);
    if ((tid & 63) == 0) wtot[tid >> 6] = tv;
  }
  __syncthreads();
  if (tid == 0) *totO = wtot[0] + wtot[1];
}

// ---------------- K2: min-max-normalized vectors into paired record fields ----------------
__device__ __forceinline__ float k2_raw(const float* __restrict__ ws, int type, int c0, int i, int L) {
  int bc = i / L, x = i - bc * L;
  int b = bc >> 5;                     // CC == 32
  if (type == 0) return ws[QS_OFF + b * CC + c0] * ws[KR_OFF + bc * HH + x] + HH * EPSF;
  if (type == 1) return ws[QR_OFF + (b * CC + c0) * HH + x] * ws[KS_OFF + bc] + HH * EPSF;
  if (type == 2) return ws[QS_OFF + b * CC + c0] * ws[KC_OFF + bc * WW + x] + WW * EPSF;
  return ws[QC_OFF + (b * CC + c0) * WW + x] * ws[KS_OFF + bc] + WW * EPSF;
}

__global__ __launch_bounds__(256) void k2_vec_norm(float* __restrict__ ws) {
  int c0 = blockIdx.x >> 2, type = blockIdx.x & 3;
  int L = (type < 2) ? HH : WW;
  int N = BC * L;
  int tid = threadIdx.x;
  float mx = -FLT_MAX, mn = FLT_MAX;
  for (int i = tid; i < N; i += 256) {
    float v = k2_raw(ws, type, c0, i, L);
    mx = fmaxf(mx, v); mn = fminf(mn, v);
  }
  mx = blkmax4(mx);
  mn = -blkmax4(-mn);
  float scale = rcpf(mx - mn);
  float fold = (type < 2) ? LOG2E : 1.0f;      // m-vectors carry the log2e factor
  int fieldbase = (type < 2) ? (type & 1) : (192 + (type & 1));
  for (int i = tid; i < N; i += 256) {
    int bc = i / L, x = i - bc * L;
    float v = k2_raw(ws, type, c0, i, L);
    ws[REC_OFF + (size_t)(c0 * BC + bc) * RECSZ + fieldbase + 2 * x] =
        (2.0f + (v - mn) * scale) * fold;
  }
}

// ---------------- K3: per (c0,plane); wave t owns term t; 3 register passes, 1 barrier ----------------
// t0=(m_r,n_r) t1=(m_r,n_c) t2=(m_c,n_r) t3=(m_c,n_c)
__global__ __launch_bounds__(256) void k3_rc(float* __restrict__ ws) {
  int vb = blockIdx.x;                 // c0*BC + plane
  int c0 = vb >> 6;                    // BC == 64
  float* rec = ws + REC_OFF + (size_t)vb * RECSZ;
  int tid = threadIdx.x;
  int t = tid >> 6, l = tid & 63;
  int msel = t >> 1, nsel = t & 1;
  __shared__ float mbuf[2 * HH];       // (m_r,m_c) pairs (×log2e)
  __shared__ float nbuf[2 * WW];       // (n_r,n_c) pairs
  __shared__ float rCs[4][WW];         // per-term 1/colsum
  if (tid < 2 * HH) mbuf[tid] = rec[tid];
  nbuf[tid] = rec[192 + tid];
  __syncthreads();                     // the only barrier
  // ---- pass 1: column sums (lane owns cols l, l+64) ----
  float n0 = nbuf[2 * l + nsel];
  float n1 = nbuf[2 * (l + 64) + nsel];
  float cs0 = 0.f, cs1 = 0.f;
  #pragma unroll 8
  for (int h = 0; h < HH; ++h) {
    float m = mbuf[2 * h + msel];
    cs0 += e2(m * n0);
    cs1 += e2(m * n1);
  }
  float rc0 = rcpf(cs0), rc1 = rcpf(cs1);
  rCs[t][l] = rc0; rCs[t][l + 64] = rc1;   // same-wave consumers only
  rec[832 + 4 * l + t] = rc0;
  rec[832 + 4 * (l + 64) + t] = rc1;
  // ---- pass 2: row sums; lane handles half-rows (h0,hf),(h0+32,hf),(h0+64,hf) ----
  int h0 = l >> 1, hf = l & 1;
  float m0 = mbuf[2 * h0 + msel];
  float m1 = mbuf[2 * (h0 + 32) + msel];
  float m2 = mbuf[2 * (h0 + 64) + msel];
  const float* nb = nbuf + 128 * hf + nsel;
  float s0 = 0.f, s1 = 0.f, s2 = 0.f;
  #pragma unroll 8
  for (int j = 0; j < 64; ++j) {
    float n = nb[2 * j];
    s0 += e2(m0 * n);
    s1 += e2(m1 * n);
    s2 += e2(m2 * n);
  }
  s0 += __shfl_xor(s0, 1, 64);         // partner l^1 has the other w-half, same rows
  s1 += __shfl_xor(s1, 1, 64);
  s2 += __shfl_xor(s2, 1, 64);
  float rr0 = rcpf(s0), rr1 = rcpf(s1), rr2 = rcpf(s2);
  if (hf == 0) {
    rec[448 + 4 * h0 + t] = rr0;
    rec[448 + 4 * (h0 + 32) + t] = rr1;
    rec[448 + 4 * (h0 + 64) + t] = rr2;
  }
  // ---- pass 3: rcmax over e*(rR+rC); same half-row ownership, rr in regs ----
  const float* rcb = &rCs[t][64 * hf];
  float mx = 0.f;
  #pragma unroll 8
  for (int j = 0; j < 64; ++j) {
    float n = nb[2 * j];
    float rc = rcb[j];
    mx = fmaxf(mx, e2(m0 * n) * (rr0 + rc));
    mx = fmaxf(mx, e2(m1 * n) * (rr1 + rc));
    mx = fmaxf(mx, e2(m2 * n) * (rr2 + rc));
  }
  #pragma unroll
  for (int o = 1; o < 64; o <<= 1) mx = fmaxf(mx, __shfl_xor(mx, o, 64));
  if (l == 0)
    atomicMax(reinterpret_cast<unsigned int*>(ws + MX_OFF + c0 * 4 + t), __float_as_uint(mx));
}

// ---------------- K4: channel-group split, direct loads, no LDS staging, no barriers ----------------
#define ELEMS 2
#define TILES 24                       // 256*ELEMS*TILES == HW
#define NCG 2
#define CG (CC/NCG)                    // 16 channels per block
__global__ __launch_bounds__(256) void k4_score(const float* __restrict__ values,
                                                float* __restrict__ ws,
                                                float* __restrict__ out) {
  int bx = blockIdx.x;                 // ((cb*TILES)+tile)*NCG + cg
  int cg = bx & (NCG - 1);
  int t2 = bx >> 1;
  int tile = t2 % TILES;
  int cb = t2 / TILES;
  int b = cb & 1, c0 = cb >> 1;
  int tid = threadIdx.x;
  int base = tile * 512;               // 4 rows per block
  int w = tid & 127;
  int h0 = tile * 4 + (tid >> 7);      // j -> rows h0 + 2j
  float im0 = rcpf(ws[MX_OFF + c0 * 4 + 0]);
  float im1 = rcpf(ws[MX_OFF + c0 * 4 + 1]);
  float im2 = rcpf(ws[MX_OFF + c0 * 4 + 2]);
  float im3 = rcpf(ws[MX_OFF + c0 * 4 + 3]);
  const float* rec0 = ws + REC_OFF + (size_t)(c0 * BC + b * CC) * RECSZ;
  const float* vsrc0 = values + (size_t)(b * CC) * HW + base + tid;
  float* sbase = out + (size_t)NPLANE + (size_t)(b * CC) * HW + base + tid;
  bool writeS = (c0 == CC - 1);
  float U0 = 0.f, U1 = 0.f, smaxl = 0.f;
  #pragma unroll 2
  for (int c = cg * CG; c < cg * CG + CG; ++c) {
    const float* rec = rec0 + (size_t)c * RECSZ;
    float2 n2 = *(const float2*)(rec + 192 + 2 * w);      // coalesced
    float4 c4 = *(const float4*)(rec + 832 + 4 * w);      // coalesced
    float A0 = c4.x * im0, A1 = c4.y * im1, A2 = c4.z * im2, A3 = c4.w * im3;
    const float* vsrc = vsrc0 + (size_t)c * HW;
    #pragma unroll
    for (int j = 0; j < ELEMS; ++j) {
      int h = h0 + 2 * j;
      float2 m2 = *(const float2*)(rec + 2 * h);          // 2 addrs/wave -> L1 broadcast
      float4 r4 = *(const float4*)(rec + 448 + 4 * h);
      float gx = fmaf(r4.x, im0, A0);
      float gy = fmaf(r4.y, im1, A1);
      float gz = fmaf(r4.z, im2, A2);
      float gw = fmaf(r4.w, im3, A3);
      float sc = e2(m2.x * n2.x) * gx + e2(m2.x * n2.y) * gy
               + e2(m2.y * n2.x) * gz + e2(m2.y * n2.y) * gw;
      smaxl = fmaxf(smaxl, sc);
      float uv = sc * vsrc[256 * j];
      if (j == 0) U0 += uv; else U1 += uv;
      if (writeS) sbase[(size_t)c * HW + 256 * j] = sc;
    }
  }
  float* zt = (cg == 0 ? out : ws + PZ_OFF) + (size_t)(b * CC + c0) * HW + base + tid;
  zt[0] = U0;
  zt[256] = U1;
  smaxl = blkmax4(smaxl);
  if (tid == 0)
    atomicMax(reinterpret_cast<unsigned int*>(ws + SMX_OFF + c0), __float_as_uint(smaxl));
}

// ---------------- K5: combine partial z, scale by 1/smax ----------------
__global__ __launch_bounds__(256) void k5_final(float* __restrict__ out,
                                                const float* __restrict__ ws) {
  float ism_last = rcpf(ws[SMX_OFF + CC - 1]);
  const float* pz = ws + PZ_OFF;
  int i0 = blockIdx.x * 256 + threadIdx.x;
  int stride = gridDim.x * 256;
  for (int i = i0; i < NPLANE; i += stride) {
    int c0 = (i / HW) & (CC - 1);      // (b*CC + c0) & 31 == c0
    out[i] = (out[i] + pz[i]) * rcpf(ws[SMX_OFF + c0]);
  }
  for (int i = i0; i < NPLANE; i += stride) {
    out[NPLANE + i] *= ism_last;
  }
}

extern "C" void kernel_launch(void* const* d_in, const int* in_sizes, int n_in,
                              void* d_out, int out_size, void* d_ws, size_t ws_size,
                              hipStream_t stream) {
  const float* q = (const float*)d_in[0];
  const float* k = (const float*)d_in[1];
  const float* v = (const float*)d_in[2];
  float* out = (float*)d_out;
  float* ws = (float*)d_ws;
  // zero only the atomic-max slots (rcmax[32][4] + smax[32])
  hipMemsetAsync((char*)d_ws + (size_t)MX_OFF * 4, 0, (size_t)(CC * 4 + CC) * 4, stream);
  k1_plane_sums<<<2 * BC, 256, 0, stream>>>(q, k, ws);
  k2_vec_norm<<<CC * 4, 256, 0, stream>>>(ws);
  k3_rc<<<CC * BC, 256, 0, stream>>>(ws);
  k4_score<<<CC * BB * TILES * NCG, 256, 0, stream>>>(v, ws, out);
  k5_final<<<2048, 256, 0, stream>>>(out, ws);
}

// Round 6
// 126.000 us; speedup vs baseline: 1.3107x; 1.3107x over previous
//
#include <hip/hip_runtime.h>
#include <float.h>

#define BB 2
#define CC 32
#define HH 96
#define WW 128
#define HW (HH*WW)           // 12288
#define BC (BB*CC)           // 64
#define NPLANE (BC*HW)       // 786432
#define EPSF 1e-6f
#define LOG2E 1.4426950408889634f

// ---- workspace layout (float offsets) ----
#define QR_OFF 0                               // [B*C][H] query row sums
#define QC_OFF (QR_OFF + BC*HH)                // [B*C][W] query col sums
#define QS_OFF (QC_OFF + BC*WW)                // [B*C]    query totals
#define KR_OFF (QS_OFF + BC)                   // [B*C][H] key row sums
#define KC_OFF (KR_OFF + BC*HH)                // [B*C][W] key col sums
#define KS_OFF (KC_OFF + BC*WW)                // [B*C]    key totals
// per-(c0,plane) packed record (vb = c0*BC + plane), RECSZ floats:
//   [0:192)    m pairs   [h][2] = (m_r, m_c), PRE-MULTIPLIED by log2e
//   [192:448)  n pairs   [w][2] = (n_r, n_c)
//   [448:832)  R4        [h][4] 1/rowsum per term
//   [832:1344) C4        [w][4] 1/colsum per term
#define REC_OFF (KS_OFF + BC)                  // == 28800
#define RECSZ 1344
#define BMX_OFF (REC_OFF + CC*BC*RECSZ)        // [2048][4] per-block term maxes (k3 out)
#define MXI_OFF (BMX_OFF + CC*BC*4)            // [C0][4]  1/rcmax (k3b out)
#define BSX_OFF (MXI_OFF + CC*4)               // [1536]   per-block smax (k4 out)
#define SMX_OFF (BSX_OFF + 1536)               // [C0]     smax (k4b out)
// total = SMX_OFF + CC ≈ 2791200 floats ≈ 11.2 MB

__device__ __forceinline__ float rcpf(float x) { return __builtin_amdgcn_rcpf(x); }
__device__ __forceinline__ float e2(float x) { return __builtin_amdgcn_exp2f(x); }

// block-wide max, 256 threads = 4 waves of 64
__device__ __forceinline__ float blkmax4(float v) {
  __shared__ float sred[4];
  #pragma unroll
  for (int o = 32; o > 0; o >>= 1) v = fmaxf(v, __shfl_xor(v, o, 64));
  if ((threadIdx.x & 63) == 0) sred[threadIdx.x >> 6] = v;
  __syncthreads();
  float r = fmaxf(fmaxf(sred[0], sred[1]), fmaxf(sred[2], sred[3]));
  __syncthreads();
  return r;
}

// ---------------- K1: per-plane row/col/total sums (queries and keys) ----------------
__global__ __launch_bounds__(256) void k1_plane_sums(const float* __restrict__ q,
                                                     const float* __restrict__ k,
                                                     float* __restrict__ ws) {
  int pb = blockIdx.x;                 // [0, 2*BC): first BC = queries, rest = keys
  int plane = pb & (BC - 1);
  const float* src = (pb < BC ? q : k) + (size_t)plane * HW;
  float* rowO = ws + (pb < BC ? QR_OFF : KR_OFF) + plane * HH;
  float* colO = ws + (pb < BC ? QC_OFF : KC_OFF) + plane * WW;
  float* totO = ws + (pb < BC ? QS_OFF : KS_OFF) + plane;
  __shared__ float cp[4 * WW];
  __shared__ float rsh[HH];
  __shared__ float wtot[2];
  int tid = threadIdx.x;
  int u = tid >> 6, l = tid & 63;
  float csum0 = 0.f, csum1 = 0.f;
  #pragma unroll 4
  for (int r = 0; r < 24; ++r) {
    int h = u * 24 + r;
    float v0 = src[h * WW + l];
    float v1 = src[h * WW + l + 64];
    csum0 += v0; csum1 += v1;
    float rs = v0 + v1;
    #pragma unroll
    for (int o = 1; o < 64; o <<= 1) rs += __shfl_xor(rs, o, 64);
    if (l == 0) { rowO[h] = rs; rsh[h] = rs; }
  }
  cp[u * WW + l] = csum0;
  cp[u * WW + l + 64] = csum1;
  __syncthreads();
  if (tid < WW) colO[tid] = cp[tid] + cp[WW + tid] + cp[2 * WW + tid] + cp[3 * WW + tid];
  float tv = (tid < HH) ? rsh[tid] : 0.f;
  if (tid < 128) {
    #pragma unroll
    for (int o = 1; o < 64; o <<= 1) tv += __shfl_xor(tv, o, 64);
    if ((tid & 63) == 0) wtot[tid >> 6] = tv;
  }
  __syncthreads();
  if (tid == 0) *totO = wtot[0] + wtot[1];
}

// ---------------- K2: min-max-normalized vectors into paired record fields ----------------
__device__ __forceinline__ float k2_raw(const float* __restrict__ ws, int type, int c0, int i, int L) {
  int bc = i / L, x = i - bc * L;
  int b = bc >> 5;                     // CC == 32
  if (type == 0) return ws[QS_OFF + b * CC + c0] * ws[KR_OFF + bc * HH + x] + HH * EPSF;
  if (type == 1) return ws[QR_OFF + (b * CC + c0) * HH + x] * ws[KS_OFF + bc] + HH * EPSF;
  if (type == 2) return ws[QS_OFF + b * CC + c0] * ws[KC_OFF + bc * WW + x] + WW * EPSF;
  return ws[QC_OFF + (b * CC + c0) * WW + x] * ws[KS_OFF + bc] + WW * EPSF;
}

__global__ __launch_bounds__(256) void k2_vec_norm(float* __restrict__ ws) {
  int c0 = blockIdx.x >> 2, type = blockIdx.x & 3;
  int L = (type < 2) ? HH : WW;
  int N = BC * L;
  int tid = threadIdx.x;
  float mx = -FLT_MAX, mn = FLT_MAX;
  for (int i = tid; i < N; i += 256) {
    float v = k2_raw(ws, type, c0, i, L);
    mx = fmaxf(mx, v); mn = fminf(mn, v);
  }
  mx = blkmax4(mx);
  mn = -blkmax4(-mn);
  float scale = rcpf(mx - mn);
  float fold = (type < 2) ? LOG2E : 1.0f;      // m-vectors carry the log2e factor
  int fieldbase = (type < 2) ? (type & 1) : (192 + (type & 1));
  for (int i = tid; i < N; i += 256) {
    int bc = i / L, x = i - bc * L;
    float v = k2_raw(ws, type, c0, i, L);
    ws[REC_OFF + (size_t)(c0 * BC + bc) * RECSZ + fieldbase + 2 * x] =
        (2.0f + (v - mn) * scale) * fold;
  }
}

// ---------------- K3: per (c0,plane); wave t owns term t; 3 register passes, 1 barrier, no atomics ----------------
// t0=(m_r,n_r) t1=(m_r,n_c) t2=(m_c,n_r) t3=(m_c,n_c)
__global__ __launch_bounds__(256) void k3_rc(float* __restrict__ ws) {
  int vb = blockIdx.x;                 // c0*BC + plane
  float* rec = ws + REC_OFF + (size_t)vb * RECSZ;
  int tid = threadIdx.x;
  int t = tid >> 6, l = tid & 63;
  int msel = t >> 1, nsel = t & 1;
  __shared__ __align__(16) float mbuf[2 * HH];  // (m_r,m_c) pairs (×log2e)
  __shared__ __align__(16) float nbuf[2 * WW];  // (n_r,n_c) pairs
  __shared__ float rCs[4][WW];                  // per-term 1/colsum (wave-local use)
  if (tid < 2 * HH) mbuf[tid] = rec[tid];
  nbuf[tid] = rec[192 + tid];
  __syncthreads();                     // the only barrier
  // ---- pass 1: column sums (lane owns cols l, l+64); b128 m reads + uniform select ----
  float n0 = nbuf[2 * l + nsel];
  float n1 = nbuf[2 * (l + 64) + nsel];
  float cs0 = 0.f, cs1 = 0.f;
  #pragma unroll 8
  for (int h2 = 0; h2 < HH; h2 += 2) {
    float4 mp = *(const float4*)&mbuf[2 * h2];
    float ma = msel ? mp.y : mp.x;
    float mb = msel ? mp.w : mp.z;
    cs0 += e2(ma * n0) + e2(mb * n0);
    cs1 += e2(ma * n1) + e2(mb * n1);
  }
  float rc0 = rcpf(cs0), rc1 = rcpf(cs1);
  rCs[t][l] = rc0; rCs[t][l + 64] = rc1;
  rec[832 + 4 * l + t] = rc0;
  rec[832 + 4 * (l + 64) + t] = rc1;
  // ---- pass 2: row sums; lane owns half-rows (h0,hf),(h0+32,hf),(h0+64,hf) ----
  int h0 = l >> 1, hf = l & 1;
  float m0 = mbuf[2 * h0 + msel];
  float m1 = mbuf[2 * (h0 + 32) + msel];
  float m2 = mbuf[2 * (h0 + 64) + msel];
  const float* nb = nbuf + 128 * hf;   // pairs for w in [64hf, 64hf+64)
  float s0 = 0.f, s1 = 0.f, s2 = 0.f;
  #pragma unroll 8
  for (int j = 0; j < 64; j += 2) {
    float4 np = *(const float4*)&nb[2 * j];
    float na = nsel ? np.y : np.x;
    float nc = nsel ? np.w : np.z;
    s0 += e2(m0 * na) + e2(m0 * nc);
    s1 += e2(m1 * na) + e2(m1 * nc);
    s2 += e2(m2 * na) + e2(m2 * nc);
  }
  s0 += __shfl_xor(s0, 1, 64);         // partner l^1 has the other w-half, same rows
  s1 += __shfl_xor(s1, 1, 64);
  s2 += __shfl_xor(s2, 1, 64);
  float rr0 = rcpf(s0), rr1 = rcpf(s1), rr2 = rcpf(s2);
  if (hf == 0) {
    rec[448 + 4 * h0 + t] = rr0;
    rec[448 + 4 * (h0 + 32) + t] = rr1;
    rec[448 + 4 * (h0 + 64) + t] = rr2;
  }
  // ---- pass 3: rcmax over e*(rR+rC); same half-row ownership, rr in regs ----
  const float* rcb = &rCs[t][64 * hf];
  float mx = 0.f;
  #pragma unroll 8
  for (int j = 0; j < 64; j += 2) {
    float4 np = *(const float4*)&nb[2 * j];
    float na = nsel ? np.y : np.x;
    float nc = nsel ? np.w : np.z;
    float ra = rcb[j], rb = rcb[j + 1];
    mx = fmaxf(mx, fmaxf(e2(m0 * na) * (rr0 + ra), e2(m0 * nc) * (rr0 + rb)));
    mx = fmaxf(mx, fmaxf(e2(m1 * na) * (rr1 + ra), e2(m1 * nc) * (rr1 + rb)));
    mx = fmaxf(mx, fmaxf(e2(m2 * na) * (rr2 + ra), e2(m2 * nc) * (rr2 + rb)));
  }
  #pragma unroll
  for (int o = 1; o < 64; o <<= 1) mx = fmaxf(mx, __shfl_xor(mx, o, 64));
  if (l == 0) ws[BMX_OFF + vb * 4 + t] = mx;   // contention-free scratch, no atomic
}

// ---------------- K3b: reduce BMX -> 1/rcmax per (c0,t). grid 32, 256 thr ----------------
__global__ __launch_bounds__(256) void k3b_mxred(float* __restrict__ ws) {
  int c0 = blockIdx.x;
  int tid = threadIdx.x;
  __shared__ float s4[4][4];
  float v = ws[BMX_OFF + c0 * 256 + tid];      // coalesced: (vb_local = tid>>2, t = tid&3)
  #pragma unroll
  for (int o = 4; o <= 32; o <<= 1) v = fmaxf(v, __shfl_xor(v, o, 64));
  if ((tid & 63) < 4) s4[tid >> 6][tid & 3] = v;
  __syncthreads();
  if (tid < 4) {
    float m = fmaxf(fmaxf(s4[0][tid], s4[1][tid]), fmaxf(s4[2][tid], s4[3][tid]));
    ws[MXI_OFF + c0 * 4 + tid] = rcpf(m);
  }
}

// ---------------- K4: LDS-staged (768 fl) double-buffer, v prefetch, no atomics ----------------
#define ELEMS 2
#define TILES 24                       // 256*ELEMS*TILES == HW; grid 1536 = 6 blocks/CU
__global__ __launch_bounds__(256) void k4_score(const float* __restrict__ values,
                                                float* __restrict__ ws,
                                                float* __restrict__ out) {
  int bx = blockIdx.x;                 // cb*TILES + tile
  int tile = bx % TILES;
  int cb = bx / TILES;
  int b = cb & 1, c0 = cb >> 1;
  int tid = threadIdx.x;
  int base = tile * 512;               // 4 rows per block
  int w = tid & 127;
  int h0 = tile * 4 + (tid >> 7);      // j -> rows h0 + 2j
  __shared__ __align__(16) float buf[2][768];   // [0:256)=n pairs, [256:768)=C4
  float im0 = ws[MXI_OFF + c0 * 4 + 0];
  float im1 = ws[MXI_OFF + c0 * 4 + 1];
  float im2 = ws[MXI_OFF + c0 * 4 + 2];
  float im3 = ws[MXI_OFF + c0 * 4 + 3];
  const float* rec0 = ws + REC_OFF + (size_t)(c0 * BC + b * CC) * RECSZ;
  bool ldr = tid < 192;
  int sidx = (tid < 64) ? (192 + 4 * tid) : (832 + 4 * (tid - 64));
  float4 g = {0.f, 0.f, 0.f, 0.f};
  if (ldr) g = *(const float4*)(rec0 + sidx);
  if (ldr) ((float4*)buf[0])[tid] = g;
  const float* vsrc0 = values + (size_t)(b * CC) * HW + base + tid;
  float v0 = vsrc0[0], v1 = vsrc0[256];
  float* sbase = out + (size_t)NPLANE + (size_t)(b * CC) * HW + base + tid;
  bool writeS = (c0 == CC - 1);
  float U0 = 0.f, U1 = 0.f, smaxl = 0.f;
  for (int c = 0; c < CC; ++c) {
    float nv0 = 0.f, nv1 = 0.f;
    if (c + 1 < CC) {                  // issue next channel's loads early (T14)
      const float* nr = rec0 + (size_t)(c + 1) * RECSZ;
      if (ldr) g = *(const float4*)(nr + sidx);
      nv0 = vsrc0[(size_t)(c + 1) * HW];
      nv1 = vsrc0[(size_t)(c + 1) * HW + 256];
    }
    __syncthreads();                   // buf[c&1] fully staged; prior readers done
    const float* B = buf[c & 1];
    const float* rec = rec0 + (size_t)c * RECSZ;
    float2 n2 = *(const float2*)(B + 2 * w);
    float4 c4 = *(const float4*)(B + 256 + 4 * w);
    float A0 = c4.x * im0, A1 = c4.y * im1, A2 = c4.z * im2, A3 = c4.w * im3;
    #pragma unroll
    for (int j = 0; j < ELEMS; ++j) {
      int h = h0 + 2 * j;
      float2 m2 = *(const float2*)(rec + 2 * h);        // wave-uniform -> L1 broadcast
      float4 r4 = *(const float4*)(rec + 448 + 4 * h);
      float gx = fmaf(r4.x, im0, A0);
      float gy = fmaf(r4.y, im1, A1);
      float gz = fmaf(r4.z, im2, A2);
      float gw = fmaf(r4.w, im3, A3);
      float sc = e2(m2.x * n2.x) * gx + e2(m2.x * n2.y) * gy
               + e2(m2.y * n2.x) * gz + e2(m2.y * n2.y) * gw;
      smaxl = fmaxf(smaxl, sc);
      float uv = sc * (j == 0 ? v0 : v1);
      if (j == 0) U0 += uv; else U1 += uv;
      if (writeS) sbase[(size_t)c * HW + 256 * j] = sc;
    }
    if (c + 1 < CC) {                  // write-late into the other buffer
      if (ldr) ((float4*)buf[(c + 1) & 1])[tid] = g;
      v0 = nv0; v1 = nv1;
    }
  }
  float* zout = out + (size_t)(b * CC + c0) * HW + base + tid;
  zout[0] = U0;
  zout[256] = U1;
  smaxl = blkmax4(smaxl);
  if (tid == 0) ws[BSX_OFF + bx] = smaxl;      // contention-free scratch, no atomic
}

// ---------------- K4b: reduce BSX -> smax per c0. grid 32, 64 thr ----------------
__global__ __launch_bounds__(64) void k4b_smred(float* __restrict__ ws) {
  int c0 = blockIdx.x;
  int l = threadIdx.x;
  float v = (l < 2 * TILES) ? ws[BSX_OFF + c0 * (2 * TILES) + l] : 0.f;
  #pragma unroll
  for (int o = 1; o < 64; o <<= 1) v = fmaxf(v, __shfl_xor(v, o, 64));
  if (l == 0) ws[SMX_OFF + c0] = v;
}

// ---------------- K5: scale by 1/smax ----------------
__global__ __launch_bounds__(256) void k5_final(float* __restrict__ out,
                                                const float* __restrict__ ws) {
  float ism_last = rcpf(ws[SMX_OFF + CC - 1]);
  int i0 = blockIdx.x * 256 + threadIdx.x;
  int stride = gridDim.x * 256;
  for (int i = i0; i < NPLANE; i += stride) {
    int c0 = (i / HW) & (CC - 1);      // (b*CC + c0) & 31 == c0
    out[i] *= rcpf(ws[SMX_OFF + c0]);
  }
  for (int i = i0; i < NPLANE; i += stride) {
    out[NPLANE + i] *= ism_last;
  }
}

extern "C" void kernel_launch(void* const* d_in, const int* in_sizes, int n_in,
                              void* d_out, int out_size, void* d_ws, size_t ws_size,
                              hipStream_t stream) {
  const float* q = (const float*)d_in[0];
  const float* k = (const float*)d_in[1];
  const float* v = (const float*)d_in[2];
  float* out = (float*)d_out;
  float* ws = (float*)d_ws;
  k1_plane_sums<<<2 * BC, 256, 0, stream>>>(q, k, ws);
  k2_vec_norm<<<CC * 4, 256, 0, stream>>>(ws);
  k3_rc<<<CC * BC, 256, 0, stream>>>(ws);
  k3b_mxred<<<CC, 256, 0, stream>>>(ws);
  k4_score<<<CC * BB * TILES, 256, 0, stream>>>(v, ws, out);
  k4b_smred<<<CC, 64, 0, stream>>>(ws);
  k5_final<<<2048, 256, 0, stream>>>(out, ws);
}

// Round 7
// 115.134 us; speedup vs baseline: 1.4344x; 1.0944x over previous
//
#include <hip/hip_runtime.h>
#include <float.h>

#define BB 2
#define CC 32
#define HH 96
#define WW 128
#define HW (HH*WW)           // 12288
#define BC (BB*CC)           // 64
#define NPLANE (BC*HW)       // 786432
#define EPSF 1e-6f
#define LOG2E 1.4426950408889634f

// ---- workspace layout (float offsets) ----
#define QR_OFF 0                               // [B*C][H] query row sums
#define QC_OFF (QR_OFF + BC*HH)                // [B*C][W] query col sums
#define QS_OFF (QC_OFF + BC*WW)                // [B*C]    query totals
#define KR_OFF (QS_OFF + BC)                   // [B*C][H] key row sums
#define KC_OFF (KR_OFF + BC*HH)                // [B*C][W] key col sums
#define KS_OFF (KC_OFF + BC*WW)                // [B*C]    key totals
// per-(c0,plane) packed record (vb = c0*BC + plane), RECSZ floats, DE-INTERLEAVED:
//   [0:96)     m_r ×log2e    [96:192)  m_c ×log2e
//   [192:320)  n_r           [320:448) n_c
//   [448:832)  R4 [h][4]     [832:1344) C4 [w][4]
#define REC_OFF (KS_OFF + BC)                  // == 28800
#define RECSZ 1344
#define BMX_OFF (REC_OFF + CC*BC*RECSZ)        // [2048][4] per-block term maxes (k3 out)
#define BSX_OFF (BMX_OFF + CC*BC*4)            // [1536]    per-block smax (k4 out)
// total = BSX_OFF + 1536 = 2791040 floats ≈ 11.16 MB

__device__ __forceinline__ float rcpf(float x) { return __builtin_amdgcn_rcpf(x); }
__device__ __forceinline__ float e2(float x) { return __builtin_amdgcn_exp2f(x); }

__device__ __forceinline__ float blkmax4(float v) {
  __shared__ float sred[4];
  #pragma unroll
  for (int o = 32; o > 0; o >>= 1) v = fmaxf(v, __shfl_xor(v, o, 64));
  if ((threadIdx.x & 63) == 0) sred[threadIdx.x >> 6] = v;
  __syncthreads();
  float r = fmaxf(fmaxf(sred[0], sred[1]), fmaxf(sred[2], sred[3]));
  __syncthreads();
  return r;
}

// ---------------- K1: per-plane row/col/total sums (queries and keys) ----------------
__global__ __launch_bounds__(256) void k1_plane_sums(const float* __restrict__ q,
                                                     const float* __restrict__ k,
                                                     float* __restrict__ ws) {
  int pb = blockIdx.x;
  int plane = pb & (BC - 1);
  const float* src = (pb < BC ? q : k) + (size_t)plane * HW;
  float* rowO = ws + (pb < BC ? QR_OFF : KR_OFF) + plane * HH;
  float* colO = ws + (pb < BC ? QC_OFF : KC_OFF) + plane * WW;
  float* totO = ws + (pb < BC ? QS_OFF : KS_OFF) + plane;
  __shared__ float cp[4 * WW];
  __shared__ float rsh[HH];
  __shared__ float wtot[2];
  int tid = threadIdx.x;
  int u = tid >> 6, l = tid & 63;
  float csum0 = 0.f, csum1 = 0.f;
  #pragma unroll 4
  for (int r = 0; r < 24; ++r) {
    int h = u * 24 + r;
    float v0 = src[h * WW + l];
    float v1 = src[h * WW + l + 64];
    csum0 += v0; csum1 += v1;
    float rs = v0 + v1;
    #pragma unroll
    for (int o = 1; o < 64; o <<= 1) rs += __shfl_xor(rs, o, 64);
    if (l == 0) { rowO[h] = rs; rsh[h] = rs; }
  }
  cp[u * WW + l] = csum0;
  cp[u * WW + l + 64] = csum1;
  __syncthreads();
  if (tid < WW) colO[tid] = cp[tid] + cp[WW + tid] + cp[2 * WW + tid] + cp[3 * WW + tid];
  float tv = (tid < HH) ? rsh[tid] : 0.f;
  if (tid < 128) {
    #pragma unroll
    for (int o = 1; o < 64; o <<= 1) tv += __shfl_xor(tv, o, 64);
    if ((tid & 63) == 0) wtot[tid >> 6] = tv;
  }
  __syncthreads();
  if (tid == 0) *totO = wtot[0] + wtot[1];
}

// ---------------- K2: min-max-normalized vectors into de-interleaved record fields ----------------
__device__ __forceinline__ float k2_raw(const float* __restrict__ ws, int type, int c0, int i, int L) {
  int bc = i / L, x = i - bc * L;
  int b = bc >> 5;
  if (type == 0) return ws[QS_OFF + b * CC + c0] * ws[KR_OFF + bc * HH + x] + HH * EPSF;
  if (type == 1) return ws[QR_OFF + (b * CC + c0) * HH + x] * ws[KS_OFF + bc] + HH * EPSF;
  if (type == 2) return ws[QS_OFF + b * CC + c0] * ws[KC_OFF + bc * WW + x] + WW * EPSF;
  return ws[QC_OFF + (b * CC + c0) * WW + x] * ws[KS_OFF + bc] + WW * EPSF;
}

__global__ __launch_bounds__(256) void k2_vec_norm(float* __restrict__ ws) {
  int c0 = blockIdx.x >> 2, type = blockIdx.x & 3;
  int L = (type < 2) ? HH : WW;
  int N = BC * L;
  int tid = threadIdx.x;
  float mx = -FLT_MAX, mn = FLT_MAX;
  for (int i = tid; i < N; i += 256) {
    float v = k2_raw(ws, type, c0, i, L);
    mx = fmaxf(mx, v); mn = fminf(mn, v);
  }
  mx = blkmax4(mx);
  mn = -blkmax4(-mn);
  float scale = rcpf(mx - mn);
  float fold = (type < 2) ? LOG2E : 1.0f;
  int fieldbase = (type == 0) ? 0 : (type == 1) ? 96 : (type == 2) ? 192 : 320;
  for (int i = tid; i < N; i += 256) {
    int bc = i / L, x = i - bc * L;
    float v = k2_raw(ws, type, c0, i, L);
    ws[REC_OFF + (size_t)(c0 * BC + bc) * RECSZ + fieldbase + x] =
        (2.0f + (v - mn) * scale) * fold;
  }
}

// ---------------- K3: per (c0,plane); wave t owns term t; no selects, 1 barrier, no atomics ----------------
__global__ __launch_bounds__(256) void k3_rc(float* __restrict__ ws) {
  int vb = blockIdx.x;                 // c0*BC + plane
  float* rec = ws + REC_OFF + (size_t)vb * RECSZ;
  int tid = threadIdx.x;
  int t = tid >> 6, l = tid & 63;
  __shared__ __align__(16) float mbuf[2 * HH];  // [m_r | m_c] blocks (×log2e)
  __shared__ __align__(16) float nbuf[2 * WW];  // [n_r | n_c] blocks
  __shared__ __align__(16) float rCs[4][WW];
  if (tid < 2 * HH) mbuf[tid] = rec[tid];
  nbuf[tid] = rec[192 + tid];
  __syncthreads();                     // the only barrier
  const float* mv = mbuf + (t >> 1) * 96;   // wave-uniform base, no per-exp select
  const float* nv = nbuf + (t & 1) * 128;
  // ---- pass 1: column sums (lane owns cols l, l+64) ----
  float n0 = nv[l], n1 = nv[l + 64];
  float cs0 = 0.f, cs1 = 0.f;
  #pragma unroll 6
  for (int h = 0; h < HH; h += 4) {
    float4 mp = *(const float4*)&mv[h];
    cs0 += e2(mp.x * n0) + e2(mp.y * n0) + e2(mp.z * n0) + e2(mp.w * n0);
    cs1 += e2(mp.x * n1) + e2(mp.y * n1) + e2(mp.z * n1) + e2(mp.w * n1);
  }
  float rc0 = rcpf(cs0), rc1 = rcpf(cs1);
  rCs[t][l] = rc0; rCs[t][l + 64] = rc1;   // same-wave consumers only
  rec[832 + 4 * l + t] = rc0;
  rec[832 + 4 * (l + 64) + t] = rc1;
  // ---- pass 2: row sums; lane owns half-rows (h0,hf),(h0+32,hf),(h0+64,hf) ----
  int h0 = l >> 1, hf = l & 1;
  float m0 = mv[h0], m1 = mv[h0 + 32], m2 = mv[h0 + 64];
  const float* nb = nv + 64 * hf;
  float s0 = 0.f, s1 = 0.f, s2 = 0.f;
  #pragma unroll 4
  for (int j = 0; j < 64; j += 4) {
    float4 np = *(const float4*)&nb[j];
    s0 += e2(m0 * np.x) + e2(m0 * np.y) + e2(m0 * np.z) + e2(m0 * np.w);
    s1 += e2(m1 * np.x) + e2(m1 * np.y) + e2(m1 * np.z) + e2(m1 * np.w);
    s2 += e2(m2 * np.x) + e2(m2 * np.y) + e2(m2 * np.z) + e2(m2 * np.w);
  }
  s0 += __shfl_xor(s0, 1, 64);         // partner l^1 has the other w-half, same rows
  s1 += __shfl_xor(s1, 1, 64);
  s2 += __shfl_xor(s2, 1, 64);
  float rr0 = rcpf(s0), rr1 = rcpf(s1), rr2 = rcpf(s2);
  if (hf == 0) {
    rec[448 + 4 * h0 + t] = rr0;
    rec[448 + 4 * (h0 + 32) + t] = rr1;
    rec[448 + 4 * (h0 + 64) + t] = rr2;
  }
  // ---- pass 3: rcmax over e*(rR+rC); same ownership, rr in regs ----
  const float* rcb = &rCs[t][64 * hf];
  float mx = 0.f;
  #pragma unroll 4
  for (int j = 0; j < 64; j += 4) {
    float4 np = *(const float4*)&nb[j];
    float4 rc = *(const float4*)&rcb[j];
    mx = fmaxf(mx, fmaxf(e2(m0 * np.x) * (rr0 + rc.x), e2(m0 * np.y) * (rr0 + rc.y)));
    mx = fmaxf(mx, fmaxf(e2(m0 * np.z) * (rr0 + rc.z), e2(m0 * np.w) * (rr0 + rc.w)));
    mx = fmaxf(mx, fmaxf(e2(m1 * np.x) * (rr1 + rc.x), e2(m1 * np.y) * (rr1 + rc.y)));
    mx = fmaxf(mx, fmaxf(e2(m1 * np.z) * (rr1 + rc.z), e2(m1 * np.w) * (rr1 + rc.w)));
    mx = fmaxf(mx, fmaxf(e2(m2 * np.x) * (rr2 + rc.x), e2(m2 * np.y) * (rr2 + rc.y)));
    mx = fmaxf(mx, fmaxf(e2(m2 * np.z) * (rr2 + rc.z), e2(m2 * np.w) * (rr2 + rc.w)));
  }
  #pragma unroll
  for (int o = 1; o < 64; o <<= 1) mx = fmaxf(mx, __shfl_xor(mx, o, 64));
  if (l == 0) ws[BMX_OFF + vb * 4 + t] = mx;
}

// ---------------- K4: all-LDS c-loop; 4-channel staged groups; BMX reduce inlined ----------------
#define ELEMS 2
#define TILES 24                       // 256*ELEMS*TILES == HW; grid 1536 = 6 blocks/CU
#define GRP 4
__global__ __launch_bounds__(256) void k4_score(const float* __restrict__ values,
                                                float* __restrict__ ws,
                                                float* __restrict__ out) {
  int bx = blockIdx.x;                 // cb*TILES + tile
  int tile = bx % TILES;
  int cb = bx / TILES;
  int b = cb & 1, c0 = cb >> 1;
  int tid = threadIdx.x;
  int base = tile * 512;               // 4 rows per block
  int w = tid & 127;
  __shared__ __align__(16) float nS[GRP][256];    // [ch][ nr 0:128 | nc 128:256 ]
  __shared__ __align__(16) float c4S[GRP][512];   // [ch][ C4 flat ]
  __shared__ __align__(16) float mrf[CC * 24];    // [ch][ m_r[4] | m_c[4] | r4[4][4] ]
  __shared__ float s44[4][4];
  const float* rec0 = ws + REC_OFF + (size_t)(c0 * BC + b * CC) * RECSZ;
  // --- prologue: BMX reduce + mrf staging + group-0 staging, one barrier ---
  float bm = ws[BMX_OFF + c0 * 256 + tid];        // (vb_local = tid>>2, t = tid&3)
  #pragma unroll
  for (int o = 4; o <= 32; o <<= 1) bm = fmaxf(bm, __shfl_xor(bm, o, 64));
  if ((tid & 63) < 4) s44[tid >> 6][tid & 3] = bm;
  if (tid < 192) {                     // 32 ch × 6 float4: m_r rows, m_c rows, r4 rows
    int ch = tid / 6, f = tid - 6 * (tid / 6);
    const float* rsrc = rec0 + (size_t)ch * RECSZ;
    int soff = (f == 0) ? tile * 4 : (f == 1) ? 96 + tile * 4 : 448 + 16 * tile + 4 * (f - 2);
    *(float4*)&mrf[ch * 24 + f * 4] = *(const float4*)(rsrc + soff);
  }
  #pragma unroll
  for (int i = tid; i < GRP * 192; i += 256) {    // group 0: n + C4
    int chl = i / 192, rem = i - 192 * (i / 192);
    const float* rsrc = rec0 + (size_t)chl * RECSZ;
    float4 g4 = (rem < 64) ? *(const float4*)(rsrc + 192 + 4 * rem)
                           : *(const float4*)(rsrc + 832 + 4 * (rem - 64));
    if (rem < 64) *(float4*)&nS[chl][4 * rem] = g4;
    else          *(float4*)&c4S[chl][4 * (rem - 64)] = g4;
  }
  const float* vsrc0 = values + (size_t)(b * CC) * HW + base + tid;
  float v0 = vsrc0[0], v1 = vsrc0[256];
  __syncthreads();
  float im0 = rcpf(fmaxf(fmaxf(s44[0][0], s44[1][0]), fmaxf(s44[2][0], s44[3][0])));
  float im1 = rcpf(fmaxf(fmaxf(s44[0][1], s44[1][1]), fmaxf(s44[2][1], s44[3][1])));
  float im2 = rcpf(fmaxf(fmaxf(s44[0][2], s44[1][2]), fmaxf(s44[2][2], s44[3][2])));
  float im3 = rcpf(fmaxf(fmaxf(s44[0][3], s44[1][3]), fmaxf(s44[2][3], s44[3][3])));
  float* sbase = out + (size_t)NPLANE + (size_t)(b * CC) * HW + base + tid;
  bool writeS = (c0 == CC - 1);
  int r0 = tid >> 7;                   // per-wave-uniform row selector
  float U0 = 0.f, U1 = 0.f, smaxl = 0.f;
  for (int c = 0; c < CC; ++c) {
    if ((c & (GRP - 1)) == 0 && c) {   // re-stage group c/GRP
      __syncthreads();                 // prior group's readers done
      #pragma unroll
      for (int i = tid; i < GRP * 192; i += 256) {
        int chl = i / 192, rem = i - 192 * (i / 192);
        const float* rsrc = rec0 + (size_t)(c + chl) * RECSZ;
        float4 g4 = (rem < 64) ? *(const float4*)(rsrc + 192 + 4 * rem)
                               : *(const float4*)(rsrc + 832 + 4 * (rem - 64));
        if (rem < 64) *(float4*)&nS[chl][4 * rem] = g4;
        else          *(float4*)&c4S[chl][4 * (rem - 64)] = g4;
      }
      __syncthreads();
    }
    float nv0 = 0.f, nv1 = 0.f;
    if (c + 1 < CC) {                  // prefetch next channel's values
      nv0 = vsrc0[(size_t)(c + 1) * HW];
      nv1 = vsrc0[(size_t)(c + 1) * HW + 256];
    }
    int cl = c & (GRP - 1);
    float nr = nS[cl][w], nc = nS[cl][128 + w];
    float4 c4 = *(const float4*)&c4S[cl][4 * w];
    float A0 = c4.x * im0, A1 = c4.y * im1, A2 = c4.z * im2, A3 = c4.w * im3;
    const float* mc = &mrf[c * 24];
    #pragma unroll
    for (int j = 0; j < ELEMS; ++j) {
      int r = r0 + 2 * j;
      float mR = mc[r], mC = mc[4 + r];
      float4 r4 = *(const float4*)&mc[8 + 4 * r];
      float gx = fmaf(r4.x, im0, A0);
      float gy = fmaf(r4.y, im1, A1);
      float gz = fmaf(r4.z, im2, A2);
      float gw = fmaf(r4.w, im3, A3);
      float sc = e2(mR * nr) * gx + e2(mR * nc) * gy
               + e2(mC * nr) * gz + e2(mC * nc) * gw;
      smaxl = fmaxf(smaxl, sc);
      float uv = sc * (j == 0 ? v0 : v1);
      if (j == 0) U0 += uv; else U1 += uv;
      if (writeS) sbase[(size_t)c * HW + 256 * j] = sc;
    }
    v0 = nv0; v1 = nv1;
  }
  float* zout = out + (size_t)(b * CC + c0) * HW + base + tid;
  zout[0] = U0;
  zout[256] = U1;
  smaxl = blkmax4(smaxl);
  if (tid == 0) ws[BSX_OFF + bx] = smaxl;
}

// ---------------- K5: per-plane BSX reduce + scale (k4b fused in) ----------------
__global__ __launch_bounds__(256) void k5_final(float* __restrict__ out,
                                                const float* __restrict__ ws) {
  int bx = blockIdx.x;                 // p*8 + sub
  int p = bx >> 3, sub = bx & 7;       // p = b*CC + c0 (z-plane) = score-plane index
  int c0 = p & (CC - 1);
  int tid = threadIdx.x;
  __shared__ float sm[2];
  if (tid < 64) {
    int l = tid;
    float a = (l < 48) ? ws[BSX_OFF + c0 * 48 + l] : 0.f;
    float c = (l < 48) ? ws[BSX_OFF + (CC - 1) * 48 + l] : 0.f;
    #pragma unroll
    for (int o = 1; o < 64; o <<= 1) {
      a = fmaxf(a, __shfl_xor(a, o, 64));
      c = fmaxf(c, __shfl_xor(c, o, 64));
    }
    if (l == 0) { sm[0] = a; sm[1] = c; }
  }
  __syncthreads();
  float ism = rcpf(sm[0]), isml = rcpf(sm[1]);
  int off = p * HW + sub * 1536 + tid;
  #pragma unroll
  for (int j = 0; j < 6; ++j) out[off + 256 * j] *= ism;
  #pragma unroll
  for (int j = 0; j < 6; ++j) out[NPLANE + off + 256 * j] *= isml;
}

extern "C" void kernel_launch(void* const* d_in, const int* in_sizes, int n_in,
                              void* d_out, int out_size, void* d_ws, size_t ws_size,
                              hipStream_t stream) {
  const float* q = (const float*)d_in[0];
  const float* k = (const float*)d_in[1];
  const float* v = (const float*)d_in[2];
  float* out = (float*)d_out;
  float* ws = (float*)d_ws;
  k1_plane_sums<<<2 * BC, 256, 0, stream>>>(q, k, ws);
  k2_vec_norm<<<CC * 4, 256, 0, stream>>>(ws);
  k3_rc<<<CC * BC, 256, 0, stream>>>(ws);
  k4_score<<<CC * BB * TILES, 256, 0, stream>>>(v, ws, out);
  k5_final<<<BC * 8, 256, 0, stream>>>(out, ws);
}

// Round 8
// 114.216 us; speedup vs baseline: 1.4459x; 1.0080x over previous
//
#include <hip/hip_runtime.h>
#include <float.h>

#define BB 2
#define CC 32
#define HH 96
#define WW 128
#define HW (HH*WW)           // 12288
#define BC (BB*CC)           // 64
#define NPLANE (BC*HW)       // 786432
#define EPSF 1e-6f
#define LOG2E 1.4426950408889634f

// ---- workspace layout (float offsets) ----
#define QR_OFF 0                               // [B*C][H] query row sums
#define QC_OFF (QR_OFF + BC*HH)                // [B*C][W] query col sums
#define QS_OFF (QC_OFF + BC*WW)                // [B*C]    query totals
#define KR_OFF (QS_OFF + BC)                   // [B*C][H] key row sums
#define KC_OFF (KR_OFF + BC*HH)                // [B*C][W] key col sums
#define KS_OFF (KC_OFF + BC*WW)                // [B*C]    key totals
// per-(c0,plane) packed record (vb = c0*BC + plane), RECSZ floats, DE-INTERLEAVED:
//   [0:96)     m_r ×log2e    [96:192)  m_c ×log2e
//   [192:320)  n_r           [320:448) n_c
//   [448:832)  R4 [h][4]     [832:1344) C4 [w][4]
#define REC_OFF (KS_OFF + BC)                  // == 28800
#define RECSZ 1344
#define BMX_OFF (REC_OFF + CC*BC*RECSZ)        // [2048][4] per-block term maxes (k3 out)
#define BSX_OFF (BMX_OFF + CC*BC*4)            // [1536]    per-block smax (k4 out)
// total = BSX_OFF + 1536 = 2791040 floats ≈ 11.16 MB

__device__ __forceinline__ float rcpf(float x) { return __builtin_amdgcn_rcpf(x); }
__device__ __forceinline__ float e2(float x) { return __builtin_amdgcn_exp2f(x); }

__device__ __forceinline__ float blkmax4(float v) {
  __shared__ float sred[4];
  #pragma unroll
  for (int o = 32; o > 0; o >>= 1) v = fmaxf(v, __shfl_xor(v, o, 64));
  if ((threadIdx.x & 63) == 0) sred[threadIdx.x >> 6] = v;
  __syncthreads();
  float r = fmaxf(fmaxf(sred[0], sred[1]), fmaxf(sred[2], sred[3]));
  __syncthreads();
  return r;
}

// ---------------- K1: per-plane row/col/total sums (queries and keys) ----------------
__global__ __launch_bounds__(256) void k1_plane_sums(const float* __restrict__ q,
                                                     const float* __restrict__ k,
                                                     float* __restrict__ ws) {
  int pb = blockIdx.x;
  int plane = pb & (BC - 1);
  const float* src = (pb < BC ? q : k) + (size_t)plane * HW;
  float* rowO = ws + (pb < BC ? QR_OFF : KR_OFF) + plane * HH;
  float* colO = ws + (pb < BC ? QC_OFF : KC_OFF) + plane * WW;
  float* totO = ws + (pb < BC ? QS_OFF : KS_OFF) + plane;
  __shared__ float cp[4 * WW];
  __shared__ float rsh[HH];
  __shared__ float wtot[2];
  int tid = threadIdx.x;
  int u = tid >> 6, l = tid & 63;
  float csum0 = 0.f, csum1 = 0.f;
  #pragma unroll 4
  for (int r = 0; r < 24; ++r) {
    int h = u * 24 + r;
    float v0 = src[h * WW + l];
    float v1 = src[h * WW + l + 64];
    csum0 += v0; csum1 += v1;
    float rs = v0 + v1;
    #pragma unroll
    for (int o = 1; o < 64; o <<= 1) rs += __shfl_xor(rs, o, 64);
    if (l == 0) { rowO[h] = rs; rsh[h] = rs; }
  }
  cp[u * WW + l] = csum0;
  cp[u * WW + l + 64] = csum1;
  __syncthreads();
  if (tid < WW) colO[tid] = cp[tid] + cp[WW + tid] + cp[2 * WW + tid] + cp[3 * WW + tid];
  float tv = (tid < HH) ? rsh[tid] : 0.f;
  if (tid < 128) {
    #pragma unroll
    for (int o = 1; o < 64; o <<= 1) tv += __shfl_xor(tv, o, 64);
    if ((tid & 63) == 0) wtot[tid >> 6] = tv;
  }
  __syncthreads();
  if (tid == 0) *totO = wtot[0] + wtot[1];
}

// ---------------- K2: min-max-normalized vectors into de-interleaved record fields ----------------
__device__ __forceinline__ float k2_raw(const float* __restrict__ ws, int type, int c0, int i, int L) {
  int bc = i / L, x = i - bc * L;
  int b = bc >> 5;
  if (type == 0) return ws[QS_OFF + b * CC + c0] * ws[KR_OFF + bc * HH + x] + HH * EPSF;
  if (type == 1) return ws[QR_OFF + (b * CC + c0) * HH + x] * ws[KS_OFF + bc] + HH * EPSF;
  if (type == 2) return ws[QS_OFF + b * CC + c0] * ws[KC_OFF + bc * WW + x] + WW * EPSF;
  return ws[QC_OFF + (b * CC + c0) * WW + x] * ws[KS_OFF + bc] + WW * EPSF;
}

__global__ __launch_bounds__(256) void k2_vec_norm(float* __restrict__ ws) {
  int c0 = blockIdx.x >> 2, type = blockIdx.x & 3;
  int L = (type < 2) ? HH : WW;
  int N = BC * L;
  int tid = threadIdx.x;
  float mx = -FLT_MAX, mn = FLT_MAX;
  for (int i = tid; i < N; i += 256) {
    float v = k2_raw(ws, type, c0, i, L);
    mx = fmaxf(mx, v); mn = fminf(mn, v);
  }
  mx = blkmax4(mx);
  mn = -blkmax4(-mn);
  float scale = rcpf(mx - mn);
  float fold = (type < 2) ? LOG2E : 1.0f;
  int fieldbase = (type == 0) ? 0 : (type == 1) ? 96 : (type == 2) ? 192 : 320;
  for (int i = tid; i < N; i += 256) {
    int bc = i / L, x = i - bc * L;
    float v = k2_raw(ws, type, c0, i, L);
    ws[REC_OFF + (size_t)(c0 * BC + bc) * RECSZ + fieldbase + x] =
        (2.0f + (v - mn) * scale) * fold;
  }
}

// ---------------- K3: 128-thread blocks; wave u owns term pair*2+u. grid 4096 = 16 wg/CU ----------------
__global__ __launch_bounds__(128) void k3_rc(float* __restrict__ ws) {
  int g = blockIdx.x;                  // vb*2 + pair
  int vb = g >> 1, pair = g & 1;
  float* rec = ws + REC_OFF + (size_t)vb * RECSZ;
  int tid = threadIdx.x;
  int u = tid >> 6, l = tid & 63;
  int t = pair * 2 + u;                // pair selects m (t>>1), u selects n (t&1)
  __shared__ __align__(16) float mn[448];   // [m_r|m_c|n_r|n_c]
  __shared__ float rCl[2][WW];
  for (int i = tid; i < 112; i += 128) ((float4*)mn)[i] = ((const float4*)rec)[i];
  __syncthreads();
  const float* mv = mn + pair * 96;
  const float* nv = mn + 192 + u * 128;
  // ---- pass 1: column sums (lane owns cols l, l+64) ----
  float n0 = nv[l], n1 = nv[l + 64];
  float cs0 = 0.f, cs1 = 0.f;
  #pragma unroll 6
  for (int h = 0; h < HH; h += 4) {
    float4 mp = *(const float4*)&mv[h];
    cs0 += e2(mp.x * n0) + e2(mp.y * n0) + e2(mp.z * n0) + e2(mp.w * n0);
    cs1 += e2(mp.x * n1) + e2(mp.y * n1) + e2(mp.z * n1) + e2(mp.w * n1);
  }
  float rc0 = rcpf(cs0), rc1 = rcpf(cs1);
  rCl[u][l] = rc0; rCl[u][l + 64] = rc1;
  rec[832 + 4 * l + t] = rc0;
  rec[832 + 4 * (l + 64) + t] = rc1;
  // ---- pass 2: row sums; lane owns half-rows (h0,hf),(h0+32,hf),(h0+64,hf) ----
  int h0 = l >> 1, hf = l & 1;
  float m0 = mv[h0], m1 = mv[h0 + 32], m2 = mv[h0 + 64];
  const float* nb = nv + 64 * hf;
  float s0 = 0.f, s1 = 0.f, s2 = 0.f;
  #pragma unroll 4
  for (int j = 0; j < 64; j += 4) {
    float4 np = *(const float4*)&nb[j];
    s0 += e2(m0 * np.x) + e2(m0 * np.y) + e2(m0 * np.z) + e2(m0 * np.w);
    s1 += e2(m1 * np.x) + e2(m1 * np.y) + e2(m1 * np.z) + e2(m1 * np.w);
    s2 += e2(m2 * np.x) + e2(m2 * np.y) + e2(m2 * np.z) + e2(m2 * np.w);
  }
  s0 += __shfl_xor(s0, 1, 64);
  s1 += __shfl_xor(s1, 1, 64);
  s2 += __shfl_xor(s2, 1, 64);
  float rr0 = rcpf(s0), rr1 = rcpf(s1), rr2 = rcpf(s2);
  if (hf == 0) {
    rec[448 + 4 * h0 + t] = rr0;
    rec[448 + 4 * (h0 + 32) + t] = rr1;
    rec[448 + 4 * (h0 + 64) + t] = rr2;
  }
  __syncthreads();                     // rCl cross-lane visibility
  // ---- pass 3: rcmax over e*(rR+rC); same ownership, rr in regs ----
  const float* rcb = &rCl[u][64 * hf];
  float mx = 0.f;
  #pragma unroll 4
  for (int j = 0; j < 64; j += 4) {
    float4 np = *(const float4*)&nb[j];
    float4 rc = *(const float4*)&rcb[j];
    mx = fmaxf(mx, fmaxf(e2(m0 * np.x) * (rr0 + rc.x), e2(m0 * np.y) * (rr0 + rc.y)));
    mx = fmaxf(mx, fmaxf(e2(m0 * np.z) * (rr0 + rc.z), e2(m0 * np.w) * (rr0 + rc.w)));
    mx = fmaxf(mx, fmaxf(e2(m1 * np.x) * (rr1 + rc.x), e2(m1 * np.y) * (rr1 + rc.y)));
    mx = fmaxf(mx, fmaxf(e2(m1 * np.z) * (rr1 + rc.z), e2(m1 * np.w) * (rr1 + rc.w)));
    mx = fmaxf(mx, fmaxf(e2(m2 * np.x) * (rr2 + rc.x), e2(m2 * np.y) * (rr2 + rc.y)));
    mx = fmaxf(mx, fmaxf(e2(m2 * np.z) * (rr2 + rc.z), e2(m2 * np.w) * (rr2 + rc.w)));
  }
  #pragma unroll
  for (int o = 1; o < 64; o <<= 1) mx = fmaxf(mx, __shfl_xor(mx, o, 64));
  if (l == 0) ws[BMX_OFF + vb * 4 + t] = mx;
}

// ---------------- K4: all-LDS c-loop; no score writes (balanced blocks) ----------------
#define ELEMS 2
#define TILES 24                       // 256*ELEMS*TILES == HW; grid 1536 = 6 blocks/CU
#define GRP 4
__global__ __launch_bounds__(256) void k4_score(const float* __restrict__ values,
                                                float* __restrict__ ws,
                                                float* __restrict__ out) {
  int bx = blockIdx.x;                 // cb*TILES + tile
  int tile = bx % TILES;
  int cb = bx / TILES;
  int b = cb & 1, c0 = cb >> 1;
  int tid = threadIdx.x;
  int base = tile * 512;               // 4 rows per block
  int w = tid & 127;
  __shared__ __align__(16) float nS[GRP][256];    // [ch][ nr 0:128 | nc 128:256 ]
  __shared__ __align__(16) float c4S[GRP][512];   // [ch][ C4 flat ]
  __shared__ __align__(16) float mrf[CC * 24];    // [ch][ m_r[4] | m_c[4] | r4[4][4] ]
  __shared__ float s44[4][4];
  const float* rec0 = ws + REC_OFF + (size_t)(c0 * BC + b * CC) * RECSZ;
  // --- prologue: BMX reduce + mrf staging + group-0 staging, one barrier ---
  float bm = ws[BMX_OFF + c0 * 256 + tid];        // (vb_local = tid>>2, t = tid&3)
  #pragma unroll
  for (int o = 4; o <= 32; o <<= 1) bm = fmaxf(bm, __shfl_xor(bm, o, 64));
  if ((tid & 63) < 4) s44[tid >> 6][tid & 3] = bm;
  if (tid < 192) {                     // 32 ch × 6 float4: m_r rows, m_c rows, r4 rows
    int ch = tid / 6, f = tid - 6 * (tid / 6);
    const float* rsrc = rec0 + (size_t)ch * RECSZ;
    int soff = (f == 0) ? tile * 4 : (f == 1) ? 96 + tile * 4 : 448 + 16 * tile + 4 * (f - 2);
    *(float4*)&mrf[ch * 24 + f * 4] = *(const float4*)(rsrc + soff);
  }
  #pragma unroll
  for (int i = tid; i < GRP * 192; i += 256) {    // group 0: n + C4
    int chl = i / 192, rem = i - 192 * (i / 192);
    const float* rsrc = rec0 + (size_t)chl * RECSZ;
    float4 g4 = (rem < 64) ? *(const float4*)(rsrc + 192 + 4 * rem)
                           : *(const float4*)(rsrc + 832 + 4 * (rem - 64));
    if (rem < 64) *(float4*)&nS[chl][4 * rem] = g4;
    else          *(float4*)&c4S[chl][4 * (rem - 64)] = g4;
  }
  const float* vsrc0 = values + (size_t)(b * CC) * HW + base + tid;
  float v0 = vsrc0[0], v1 = vsrc0[256];
  __syncthreads();
  float im0 = rcpf(fmaxf(fmaxf(s44[0][0], s44[1][0]), fmaxf(s44[2][0], s44[3][0])));
  float im1 = rcpf(fmaxf(fmaxf(s44[0][1], s44[1][1]), fmaxf(s44[2][1], s44[3][1])));
  float im2 = rcpf(fmaxf(fmaxf(s44[0][2], s44[1][2]), fmaxf(s44[2][2], s44[3][2])));
  float im3 = rcpf(fmaxf(fmaxf(s44[0][3], s44[1][3]), fmaxf(s44[2][3], s44[3][3])));
  int r0 = tid >> 7;                   // per-wave-uniform row selector
  float U0 = 0.f, U1 = 0.f, smaxl = 0.f;
  for (int c = 0; c < CC; ++c) {
    if ((c & (GRP - 1)) == 0 && c) {   // re-stage group c/GRP
      __syncthreads();
      #pragma unroll
      for (int i = tid; i < GRP * 192; i += 256) {
        int chl = i / 192, rem = i - 192 * (i / 192);
        const float* rsrc = rec0 + (size_t)(c + chl) * RECSZ;
        float4 g4 = (rem < 64) ? *(const float4*)(rsrc + 192 + 4 * rem)
                               : *(const float4*)(rsrc + 832 + 4 * (rem - 64));
        if (rem < 64) *(float4*)&nS[chl][4 * rem] = g4;
        else          *(float4*)&c4S[chl][4 * (rem - 64)] = g4;
      }
      __syncthreads();
    }
    float nv0 = 0.f, nv1 = 0.f;
    if (c + 1 < CC) {                  // prefetch next channel's values
      nv0 = vsrc0[(size_t)(c + 1) * HW];
      nv1 = vsrc0[(size_t)(c + 1) * HW + 256];
    }
    int cl = c & (GRP - 1);
    float nr = nS[cl][w], nc = nS[cl][128 + w];
    float4 c4 = *(const float4*)&c4S[cl][4 * w];
    float A0 = c4.x * im0, A1 = c4.y * im1, A2 = c4.z * im2, A3 = c4.w * im3;
    const float* mc = &mrf[c * 24];
    #pragma unroll
    for (int j = 0; j < ELEMS; ++j) {
      int r = r0 + 2 * j;
      float mR = mc[r], mC = mc[4 + r];
      float4 r4 = *(const float4*)&mc[8 + 4 * r];
      float gx = fmaf(r4.x, im0, A0);
      float gy = fmaf(r4.y, im1, A1);
      float gz = fmaf(r4.z, im2, A2);
      float gw = fmaf(r4.w, im3, A3);
      float sc = e2(mR * nr) * gx + e2(mR * nc) * gy
               + e2(mC * nr) * gz + e2(mC * nc) * gw;
      smaxl = fmaxf(smaxl, sc);
      float uv = sc * (j == 0 ? v0 : v1);
      if (j == 0) U0 += uv; else U1 += uv;
    }
    v0 = nv0; v1 = nv1;
  }
  float* zout = out + (size_t)(b * CC + c0) * HW + base + tid;
  zout[0] = U0;
  zout[256] = U1;
  smaxl = blkmax4(smaxl);
  if (tid == 0) ws[BSX_OFF + bx] = smaxl;
}

// ---------------- K5: z-scale (512 blocks) + score recompute for c0=31 (128 blocks) ----------------
#define K5_ZB (BC * 8)                 // 512
__global__ __launch_bounds__(256) void k5_final(float* __restrict__ out,
                                                const float* __restrict__ ws) {
  int bx = blockIdx.x;
  int tid = threadIdx.x;
  if (bx < K5_ZB) {
    int p = bx >> 3, sub = bx & 7;     // p = b*CC + c0 z-plane
    int c0 = p & (CC - 1);
    __shared__ float sm;
    if (tid < 64) {
      float a = (tid < 48) ? ws[BSX_OFF + c0 * 48 + tid] : 0.f;
      #pragma unroll
      for (int o = 1; o < 64; o <<= 1) a = fmaxf(a, __shfl_xor(a, o, 64));
      if (tid == 0) sm = a;
    }
    __syncthreads();
    float ism = rcpf(sm);
    int off = p * HW + sub * 1536 + tid;
    #pragma unroll
    for (int j = 0; j < 6; ++j) out[off + 256 * j] *= ism;
  } else {
    int sp = bx - K5_ZB;               // 128 blocks: plane = sp>>1, half = sp&1
    int plane = sp >> 1, half = sp & 1;
    const float* rec = ws + REC_OFF + (size_t)((CC - 1) * BC + plane) * RECSZ;
    __shared__ __align__(16) float R[RECSZ];
    __shared__ float s44[4][4];
    __shared__ float sm;
    for (int i = tid; i < RECSZ / 4; i += 256) ((float4*)R)[i] = ((const float4*)rec)[i];
    float bm = ws[BMX_OFF + (CC - 1) * 256 + tid];
    #pragma unroll
    for (int o = 4; o <= 32; o <<= 1) bm = fmaxf(bm, __shfl_xor(bm, o, 64));
    if ((tid & 63) < 4) s44[tid >> 6][tid & 3] = bm;
    if (tid < 64) {
      float a = (tid < 48) ? ws[BSX_OFF + (CC - 1) * 48 + tid] : 0.f;
      #pragma unroll
      for (int o = 1; o < 64; o <<= 1) a = fmaxf(a, __shfl_xor(a, o, 64));
      if (tid == 0) sm = a;
    }
    __syncthreads();
    float im0 = rcpf(fmaxf(fmaxf(s44[0][0], s44[1][0]), fmaxf(s44[2][0], s44[3][0])));
    float im1 = rcpf(fmaxf(fmaxf(s44[0][1], s44[1][1]), fmaxf(s44[2][1], s44[3][1])));
    float im2 = rcpf(fmaxf(fmaxf(s44[0][2], s44[1][2]), fmaxf(s44[2][2], s44[3][2])));
    float im3 = rcpf(fmaxf(fmaxf(s44[0][3], s44[1][3]), fmaxf(s44[2][3], s44[3][3])));
    float isml = rcpf(sm);
    float* sout = out + (size_t)NPLANE + (size_t)plane * HW + half * 6144;
    #pragma unroll 4
    for (int e = tid; e < 6144; e += 256) {
      int idx = half * 6144 + e;
      int h = idx >> 7, ww = idx & 127;
      float mR = R[h], mC = R[96 + h];
      float nr = R[192 + ww], nc = R[320 + ww];
      float4 r4 = *(const float4*)&R[448 + 4 * h];
      float4 c4 = *(const float4*)&R[832 + 4 * ww];
      float A0 = c4.x * im0, A1 = c4.y * im1, A2 = c4.z * im2, A3 = c4.w * im3;
      float sc = e2(mR * nr) * fmaf(r4.x, im0, A0) + e2(mR * nc) * fmaf(r4.y, im1, A1)
               + e2(mC * nr) * fmaf(r4.z, im2, A2) + e2(mC * nc) * fmaf(r4.w, im3, A3);
      sout[e] = sc * isml;
    }
  }
}

extern "C" void kernel_launch(void* const* d_in, const int* in_sizes, int n_in,
                              void* d_out, int out_size, void* d_ws, size_t ws_size,
                              hipStream_t stream) {
  const float* q = (const float*)d_in[0];
  const float* k = (const float*)d_in[1];
  const float* v = (const float*)d_in[2];
  float* out = (float*)d_out;
  float* ws = (float*)d_ws;
  k1_plane_sums<<<2 * BC, 256, 0, stream>>>(q, k, ws);
  k2_vec_norm<<<CC * 4, 256, 0, stream>>>(ws);
  k3_rc<<<CC * BC * 2, 128, 0, stream>>>(ws);
  k4_score<<<CC * BB * TILES, 256, 0, stream>>>(v, ws, out);
  k5_final<<<K5_ZB + 128, 256, 0, stream>>>(out, ws);
}

// Round 9
// 99.831 us; speedup vs baseline: 1.6543x; 1.1441x over previous
//
#include <hip/hip_runtime.h>
#include <float.h>

#define BB 2
#define CC 32
#define HH 96
#define WW 128
#define HW (HH*WW)           // 12288
#define BC (BB*CC)           // 64
#define NPLANE (BC*HW)       // 786432
#define EPSF 1e-6f
#define LOG2E 1.4426950408889634f

// ---- workspace layout (float offsets) ----
#define QR_OFF 0                               // [B*C][H] query row sums
#define QC_OFF (QR_OFF + BC*HH)                // [B*C][W] query col sums
#define QS_OFF (QC_OFF + BC*WW)                // [B*C]    query totals
#define KR_OFF (QS_OFF + BC)                   // [B*C][H] key row sums
#define KC_OFF (KR_OFF + BC*HH)                // [B*C][W] key col sums
#define KS_OFF (KC_OFF + BC*WW)                // [B*C]    key totals
// per-(c0,plane) packed record (vb = c0*BC + plane), RECSZ floats, DE-INTERLEAVED:
//   [0:96)     m_r ×log2e    [96:192)  m_c ×log2e
//   [192:320)  n_r           [320:448) n_c
//   [448:832)  R4 [h][4]     [832:1344) C4 [w][4]
#define REC_OFF (KS_OFF + BC)                  // == 28800
#define RECSZ 1344
#define BMX_OFF (REC_OFF + CC*BC*RECSZ)        // [2048][4] per-block term maxes (k3 out)
#define BSX_OFF (BMX_OFF + CC*BC*4)            // [1536]    per-block smax (k4 out)
// total = BSX_OFF + 1536 = 2791040 floats ≈ 11.16 MB

__device__ __forceinline__ float rcpf(float x) { return __builtin_amdgcn_rcpf(x); }
__device__ __forceinline__ float e2(float x) { return __builtin_amdgcn_exp2f(x); }

typedef _Float16 h2v __attribute__((ext_vector_type(2)));
__device__ __forceinline__ unsigned pkrtz_u(float a, float b) {
  return __builtin_bit_cast(unsigned, __builtin_amdgcn_cvt_pkrtz(a, b));
}
__device__ __forceinline__ unsigned pk_add(unsigned a, unsigned b) {
  unsigned d; asm("v_pk_add_f16 %0, %1, %2" : "=v"(d) : "v"(a), "v"(b)); return d;
}
__device__ __forceinline__ unsigned pk_mul(unsigned a, unsigned b) {
  unsigned d; asm("v_pk_mul_f16 %0, %1, %2" : "=v"(d) : "v"(a), "v"(b)); return d;
}
__device__ __forceinline__ unsigned pk_max(unsigned a, unsigned b) {
  unsigned d; asm("v_pk_max_f16 %0, %1, %2" : "=v"(d) : "v"(a), "v"(b)); return d;
}
__device__ __forceinline__ float dot2acc(unsigned u, float acc) {
#if __has_builtin(__builtin_amdgcn_fdot2)
  h2v a = __builtin_bit_cast(h2v, u);
  h2v one = {(_Float16)1.0f, (_Float16)1.0f};
  return __builtin_amdgcn_fdot2(a, one, acc, false);
#else
  float lo = (float)__builtin_bit_cast(_Float16, (unsigned short)(u & 0xffff));
  float hi = (float)__builtin_bit_cast(_Float16, (unsigned short)(u >> 16));
  return acc + lo + hi;
#endif
}
__device__ __forceinline__ float h2max_f(unsigned u) {
  float lo = (float)__builtin_bit_cast(_Float16, (unsigned short)(u & 0xffff));
  float hi = (float)__builtin_bit_cast(_Float16, (unsigned short)(u >> 16));
  return fmaxf(lo, hi);
}

__device__ __forceinline__ float blkmax4(float v) {
  __shared__ float sred[4];
  #pragma unroll
  for (int o = 32; o > 0; o >>= 1) v = fmaxf(v, __shfl_xor(v, o, 64));
  if ((threadIdx.x & 63) == 0) sred[threadIdx.x >> 6] = v;
  __syncthreads();
  float r = fmaxf(fmaxf(sred[0], sred[1]), fmaxf(sred[2], sred[3]));
  __syncthreads();
  return r;
}

// ---------------- K1: per-plane row/col/total sums (queries and keys) ----------------
__global__ __launch_bounds__(256) void k1_plane_sums(const float* __restrict__ q,
                                                     const float* __restrict__ k,
                                                     float* __restrict__ ws) {
  int pb = blockIdx.x;
  int plane = pb & (BC - 1);
  const float* src = (pb < BC ? q : k) + (size_t)plane * HW;
  float* rowO = ws + (pb < BC ? QR_OFF : KR_OFF) + plane * HH;
  float* colO = ws + (pb < BC ? QC_OFF : KC_OFF) + plane * WW;
  float* totO = ws + (pb < BC ? QS_OFF : KS_OFF) + plane;
  __shared__ float cp[4 * WW];
  __shared__ float rsh[HH];
  __shared__ float wtot[2];
  int tid = threadIdx.x;
  int u = tid >> 6, l = tid & 63;
  float csum0 = 0.f, csum1 = 0.f;
  #pragma unroll 4
  for (int r = 0; r < 24; ++r) {
    int h = u * 24 + r;
    float v0 = src[h * WW + l];
    float v1 = src[h * WW + l + 64];
    csum0 += v0; csum1 += v1;
    float rs = v0 + v1;
    #pragma unroll
    for (int o = 1; o < 64; o <<= 1) rs += __shfl_xor(rs, o, 64);
    if (l == 0) { rowO[h] = rs; rsh[h] = rs; }
  }
  cp[u * WW + l] = csum0;
  cp[u * WW + l + 64] = csum1;
  __syncthreads();
  if (tid < WW) colO[tid] = cp[tid] + cp[WW + tid] + cp[2 * WW + tid] + cp[3 * WW + tid];
  float tv = (tid < HH) ? rsh[tid] : 0.f;
  if (tid < 128) {
    #pragma unroll
    for (int o = 1; o < 64; o <<= 1) tv += __shfl_xor(tv, o, 64);
    if ((tid & 63) == 0) wtot[tid >> 6] = tv;
  }
  __syncthreads();
  if (tid == 0) *totO = wtot[0] + wtot[1];
}

// ---------------- K2: min-max-normalized vectors into de-interleaved record fields ----------------
__device__ __forceinline__ float k2_raw(const float* __restrict__ ws, int type, int c0, int i, int L) {
  int bc = i / L, x = i - bc * L;
  int b = bc >> 5;
  if (type == 0) return ws[QS_OFF + b * CC + c0] * ws[KR_OFF + bc * HH + x] + HH * EPSF;
  if (type == 1) return ws[QR_OFF + (b * CC + c0) * HH + x] * ws[KS_OFF + bc] + HH * EPSF;
  if (type == 2) return ws[QS_OFF + b * CC + c0] * ws[KC_OFF + bc * WW + x] + WW * EPSF;
  return ws[QC_OFF + (b * CC + c0) * WW + x] * ws[KS_OFF + bc] + WW * EPSF;
}

__global__ __launch_bounds__(256) void k2_vec_norm(float* __restrict__ ws) {
  int c0 = blockIdx.x >> 2, type = blockIdx.x & 3;
  int L = (type < 2) ? HH : WW;
  int N = BC * L;
  int tid = threadIdx.x;
  float mx = -FLT_MAX, mn = FLT_MAX;
  for (int i = tid; i < N; i += 256) {
    float v = k2_raw(ws, type, c0, i, L);
    mx = fmaxf(mx, v); mn = fminf(mn, v);
  }
  mx = blkmax4(mx);
  mn = -blkmax4(-mn);
  float scale = rcpf(mx - mn);
  float fold = (type < 2) ? LOG2E : 1.0f;
  int fieldbase = (type == 0) ? 0 : (type == 1) ? 96 : (type == 2) ? 192 : 320;
  for (int i = tid; i < N; i += 256) {
    int bc = i / L, x = i - bc * L;
    float v = k2_raw(ws, type, c0, i, L);
    ws[REC_OFF + (size_t)(c0 * BC + bc) * RECSZ + fieldbase + x] =
        (2.0f + (v - mn) * scale) * fold;
  }
}

// ---------------- K3: one block per (vb,t); e computed ONCE, fp16 LDS; packed reduce ----------------
#define EPH 136                        // halves per row (272B, 16B-aligned)
__global__ __launch_bounds__(256) void k3_rc(float* __restrict__ ws) {
  int g = blockIdx.x;                  // vb*4 + t
  int vb = g >> 2, t = g & 3;
  float* rec = ws + REC_OFF + (size_t)vb * RECSZ;
  int tid = threadIdx.x;
  int u = tid >> 6, l = tid & 63;
  __shared__ __align__(16) unsigned short eh[HH * EPH];   // 26112 B fp16 e
  __shared__ __align__(16) float mncp[512];               // m[0:96] n[96:224]; later cpart[4][128]
  __shared__ __align__(16) unsigned short rch[128];       // fp16 4096*rC
  __shared__ float wmx[3];
  const float* mv = rec + (t >> 1) * 96;
  const float* nv = rec + 192 + (t & 1) * 128;
  if (tid < 224) mncp[tid] = (tid < 96) ? mv[tid] : nv[tid - 96];
  __syncthreads();                                        // B1
  // ---- pass A: wave u owns rows 24u..24u+23; lane owns cols 2l,2l+1. e once. ----
  float n0 = mncp[96 + 2 * l], n1 = mncp[96 + 2 * l + 1];
  float cs0 = 0.f, cs1 = 0.f;
  #pragma unroll 6
  for (int r = 0; r < 24; ++r) {
    int h = u * 24 + r;
    float m = mncp[h];
    float e0 = e2(m * n0);
    float e1 = e2(m * n1);
    cs0 += e0; cs1 += e1;
    *(unsigned*)&eh[h * EPH + 2 * l] = pkrtz_u(e0, e1);
  }
  __syncthreads();                                        // B2 (mn reads done, eh complete)
  mncp[u * 128 + 2 * l] = cs0;
  mncp[u * 128 + 2 * l + 1] = cs1;
  __syncthreads();                                        // B3 (cpart ready)
  if (tid < 64) {                      // lane owns cols 2tid, 2tid+1
    int w0 = 2 * tid, w1 = w0 + 1;
    float rc0 = rcpf(mncp[w0] + mncp[128 + w0] + mncp[256 + w0] + mncp[384 + w0]);
    float rc1 = rcpf(mncp[w1] + mncp[128 + w1] + mncp[256 + w1] + mncp[384 + w1]);
    rec[832 + 4 * w0 + t] = rc0;
    rec[832 + 4 * w1 + t] = rc1;
    ((unsigned*)rch)[tid] = pkrtz_u(rc0 * 4096.f, rc1 * 4096.f);
  }
  __syncthreads();                                        // B4 (rch ready)
  // ---- pass B+C: lanes 0-191 own half-rows (row=tid>>1, hf=tid&1) ----
  float mx = 0.f;
  if (tid < 192) {
    int row = tid >> 1, hf = tid & 1;
    const uint4* ep = (const uint4*)&eh[row * EPH + hf * 64];
    float s = 0.f;
    #pragma unroll
    for (int j = 0; j < 8; ++j) {
      uint4 ev = ep[j];
      s = dot2acc(ev.x, s); s = dot2acc(ev.y, s);
      s = dot2acc(ev.z, s); s = dot2acc(ev.w, s);
    }
    s += __shfl_xor(s, 1, 64);         // partner has other w-half of same row
    float rr = rcpf(s);
    if (hf == 0) rec[448 + 4 * row + t] = rr;
    unsigned rr2 = pkrtz_u(rr * 4096.f, rr * 4096.f);
    unsigned mxu = 0;
    const uint4* cp2 = (const uint4*)&rch[hf * 64];
    #pragma unroll
    for (int j = 0; j < 8; ++j) {
      uint4 ev = ep[j];
      uint4 cv = cp2[j];
      mxu = pk_max(mxu, pk_mul(ev.x, pk_add(cv.x, rr2)));
      mxu = pk_max(mxu, pk_mul(ev.y, pk_add(cv.y, rr2)));
      mxu = pk_max(mxu, pk_mul(ev.z, pk_add(cv.z, rr2)));
      mxu = pk_max(mxu, pk_mul(ev.w, pk_add(cv.w, rr2)));
    }
    mx = h2max_f(mxu) * (1.0f / 4096.f);
    #pragma unroll
    for (int o = 1; o < 64; o <<= 1) mx = fmaxf(mx, __shfl_xor(mx, o, 64));
    if ((tid & 63) == 0) wmx[tid >> 6] = mx;
  }
  __syncthreads();                                        // B5
  if (tid == 0) ws[BMX_OFF + vb * 4 + t] = fmaxf(fmaxf(wmx[0], wmx[1]), wmx[2]);
}

// ---------------- K4: all-LDS c-loop; R4/C4 pre-scaled by im at stage time ----------------
#define ELEMS 2
#define TILES 24                       // 256*ELEMS*TILES == HW; grid 1536 = 6 blocks/CU
#define GRP 4
__global__ __launch_bounds__(256) void k4_score(const float* __restrict__ values,
                                                float* __restrict__ ws,
                                                float* __restrict__ out) {
  int bx = blockIdx.x;                 // cb*TILES + tile
  int tile = bx % TILES;
  int cb = bx / TILES;
  int b = cb & 1, c0 = cb >> 1;
  int tid = threadIdx.x;
  int base = tile * 512;               // 4 rows per block
  int w = tid & 127;
  __shared__ __align__(16) float nS[GRP][256];    // [ch][ nr 0:128 | nc 128:256 ]
  __shared__ __align__(16) float c4S[GRP][512];   // [ch][ C4×im flat ]
  __shared__ __align__(16) float mrf[CC * 24];    // [ch][ m_r[4] | m_c[4] | r4×im[16] ]
  __shared__ float s44[4][4];
  const float* rec0 = ws + REC_OFF + (size_t)(c0 * BC + b * CC) * RECSZ;
  // --- prologue A: BMX reduce + raw mrf stage + v loads ---
  float bm = ws[BMX_OFF + c0 * 256 + tid];
  #pragma unroll
  for (int o = 4; o <= 32; o <<= 1) bm = fmaxf(bm, __shfl_xor(bm, o, 64));
  if ((tid & 63) < 4) s44[tid >> 6][tid & 3] = bm;
  if (tid < 192) {
    int ch = tid / 6, f = tid - 6 * (tid / 6);
    const float* rsrc = rec0 + (size_t)ch * RECSZ;
    int soff = (f == 0) ? tile * 4 : (f == 1) ? 96 + tile * 4 : 448 + 16 * tile + 4 * (f - 2);
    *(float4*)&mrf[ch * 24 + f * 4] = *(const float4*)(rsrc + soff);
  }
  const float* vsrc0 = values + (size_t)(b * CC) * HW + base + tid;
  float v0 = vsrc0[0], v1 = vsrc0[256];
  __syncthreads();                     // B1: s44 + raw mrf visible
  float im0 = rcpf(fmaxf(fmaxf(s44[0][0], s44[1][0]), fmaxf(s44[2][0], s44[3][0])));
  float im1 = rcpf(fmaxf(fmaxf(s44[0][1], s44[1][1]), fmaxf(s44[2][1], s44[3][1])));
  float im2 = rcpf(fmaxf(fmaxf(s44[0][2], s44[1][2]), fmaxf(s44[2][2], s44[3][2])));
  float im3 = rcpf(fmaxf(fmaxf(s44[0][3], s44[1][3]), fmaxf(s44[2][3], s44[3][3])));
  // scale mrf r4 region in place (distinct entries per thread)
  for (int i = tid; i < CC * 16; i += 256) {
    int ch = i >> 4, kk = i & 15, tt = kk & 3;
    float sel = tt == 0 ? im0 : tt == 1 ? im1 : tt == 2 ? im2 : im3;
    mrf[ch * 24 + 8 + kk] *= sel;
  }
  // stage group 0 (c4 scaled)
  #pragma unroll
  for (int i = tid; i < GRP * 192; i += 256) {
    int chl = i / 192, rem = i - 192 * (i / 192);
    const float* rsrc = rec0 + (size_t)chl * RECSZ;
    if (rem < 64) {
      *(float4*)&nS[chl][4 * rem] = *(const float4*)(rsrc + 192 + 4 * rem);
    } else {
      float4 g4 = *(const float4*)(rsrc + 832 + 4 * (rem - 64));
      g4.x *= im0; g4.y *= im1; g4.z *= im2; g4.w *= im3;
      *(float4*)&c4S[chl][4 * (rem - 64)] = g4;
    }
  }
  __syncthreads();                     // B2: group 0 + scaled mrf visible
  int r0 = tid >> 7;
  float U0 = 0.f, U1 = 0.f, smaxl = 0.f;
  for (int c = 0; c < CC; ++c) {
    if ((c & (GRP - 1)) == 0 && c) {
      __syncthreads();
      #pragma unroll
      for (int i = tid; i < GRP * 192; i += 256) {
        int chl = i / 192, rem = i - 192 * (i / 192);
        const float* rsrc = rec0 + (size_t)(c + chl) * RECSZ;
        if (rem < 64) {
          *(float4*)&nS[chl][4 * rem] = *(const float4*)(rsrc + 192 + 4 * rem);
        } else {
          float4 g4 = *(const float4*)(rsrc + 832 + 4 * (rem - 64));
          g4.x *= im0; g4.y *= im1; g4.z *= im2; g4.w *= im3;
          *(float4*)&c4S[chl][4 * (rem - 64)] = g4;
        }
      }
      __syncthreads();
    }
    float nv0 = 0.f, nv1 = 0.f;
    if (c + 1 < CC) {
      nv0 = vsrc0[(size_t)(c + 1) * HW];
      nv1 = vsrc0[(size_t)(c + 1) * HW + 256];
    }
    int cl = c & (GRP - 1);
    float nr = nS[cl][w], nc = nS[cl][128 + w];
    float4 c4 = *(const float4*)&c4S[cl][4 * w];
    const float* mc = &mrf[c * 24];
    #pragma unroll
    for (int j = 0; j < ELEMS; ++j) {
      int r = r0 + 2 * j;
      float mR = mc[r], mC = mc[4 + r];
      float4 r4 = *(const float4*)&mc[8 + 4 * r];
      float sc = e2(mR * nr) * (r4.x + c4.x) + e2(mR * nc) * (r4.y + c4.y)
               + e2(mC * nr) * (r4.z + c4.z) + e2(mC * nc) * (r4.w + c4.w);
      smaxl = fmaxf(smaxl, sc);
      float uv = sc * (j == 0 ? v0 : v1);
      if (j == 0) U0 += uv; else U1 += uv;
    }
    v0 = nv0; v1 = nv1;
  }
  float* zout = out + (size_t)(b * CC + c0) * HW + base + tid;
  zout[0] = U0;
  zout[256] = U1;
  smaxl = blkmax4(smaxl);
  if (tid == 0) ws[BSX_OFF + bx] = smaxl;
}

// ---------------- K5: z-scale (512 blocks) + score recompute for c0=31 (128 blocks) ----------------
#define K5_ZB (BC * 8)                 // 512
__global__ __launch_bounds__(256) void k5_final(float* __restrict__ out,
                                                const float* __restrict__ ws) {
  int bx = blockIdx.x;
  int tid = threadIdx.x;
  if (bx < K5_ZB) {
    int p = bx >> 3, sub = bx & 7;     // p = b*CC + c0 z-plane
    int c0 = p & (CC - 1);
    __shared__ float sm;
    if (tid < 64) {
      float a = (tid < 48) ? ws[BSX_OFF + c0 * 48 + tid] : 0.f;
      #pragma unroll
      for (int o = 1; o < 64; o <<= 1) a = fmaxf(a, __shfl_xor(a, o, 64));
      if (tid == 0) sm = a;
    }
    __syncthreads();
    float ism = rcpf(sm);
    int off = p * HW + sub * 1536 + tid;
    #pragma unroll
    for (int j = 0; j < 6; ++j) out[off + 256 * j] *= ism;
  } else {
    int sp = bx - K5_ZB;               // 128 blocks: plane = sp>>1, half = sp&1
    int plane = sp >> 1, half = sp & 1;
    const float* rec = ws + REC_OFF + (size_t)((CC - 1) * BC + plane) * RECSZ;
    __shared__ __align__(16) float R[RECSZ];
    __shared__ float s44[4][4];
    __shared__ float sm;
    for (int i = tid; i < RECSZ / 4; i += 256) ((float4*)R)[i] = ((const float4*)rec)[i];
    float bm = ws[BMX_OFF + (CC - 1) * 256 + tid];
    #pragma unroll
    for (int o = 4; o <= 32; o <<= 1) bm = fmaxf(bm, __shfl_xor(bm, o, 64));
    if ((tid & 63) < 4) s44[tid >> 6][tid & 3] = bm;
    if (tid < 64) {
      float a = (tid < 48) ? ws[BSX_OFF + (CC - 1) * 48 + tid] : 0.f;
      #pragma unroll
      for (int o = 1; o < 64; o <<= 1) a = fmaxf(a, __shfl_xor(a, o, 64));
      if (tid == 0) sm = a;
    }
    __syncthreads();
    float im0 = rcpf(fmaxf(fmaxf(s44[0][0], s44[1][0]), fmaxf(s44[2][0], s44[3][0])));
    float im1 = rcpf(fmaxf(fmaxf(s44[0][1], s44[1][1]), fmaxf(s44[2][1], s44[3][1])));
    float im2 = rcpf(fmaxf(fmaxf(s44[0][2], s44[1][2]), fmaxf(s44[2][2], s44[3][2])));
    float im3 = rcpf(fmaxf(fmaxf(s44[0][3], s44[1][3]), fmaxf(s44[2][3], s44[3][3])));
    float isml = rcpf(sm);
    float* sout = out + (size_t)NPLANE + (size_t)plane * HW + half * 6144;
    #pragma unroll 4
    for (int e = tid; e < 6144; e += 256) {
      int idx = half * 6144 + e;
      int h = idx >> 7, ww = idx & 127;
      float mR = R[h], mC = R[96 + h];
      float nr = R[192 + ww], nc = R[320 + ww];
      float4 r4 = *(const float4*)&R[448 + 4 * h];
      float4 c4 = *(const float4*)&R[832 + 4 * ww];
      float A0 = c4.x * im0, A1 = c4.y * im1, A2 = c4.z * im2, A3 = c4.w * im3;
      float sc = e2(mR * nr) * fmaf(r4.x, im0, A0) + e2(mR * nc) * fmaf(r4.y, im1, A1)
               + e2(mC * nr) * fmaf(r4.z, im2, A2) + e2(mC * nc) * fmaf(r4.w, im3, A3);
      sout[e] = sc * isml;
    }
  }
}

extern "C" void kernel_launch(void* const* d_in, const int* in_sizes, int n_in,
                              void* d_out, int out_size, void* d_ws, size_t ws_size,
                              hipStream_t stream) {
  const float* q = (const float*)d_in[0];
  const float* k = (const float*)d_in[1];
  const float* v = (const float*)d_in[2];
  float* out = (float*)d_out;
  float* ws = (float*)d_ws;
  k1_plane_sums<<<2 * BC, 256, 0, stream>>>(q, k, ws);
  k2_vec_norm<<<CC * 4, 256, 0, stream>>>(ws);
  k3_rc<<<CC * BC * 4, 256, 0, stream>>>(ws);
  k4_score<<<CC * BB * TILES, 256, 0, stream>>>(v, ws, out);
  k5_final<<<K5_ZB + 128, 256, 0, stream>>>(out, ws);
}

// Round 10
// 98.252 us; speedup vs baseline: 1.6809x; 1.0161x over previous
//
#include <hip/hip_runtime.h>
#include <float.h>

#define BB 2
#define CC 32
#define HH 96
#define WW 128
#define HW (HH*WW)           // 12288
#define BC (BB*CC)           // 64
#define NPLANE (BC*HW)       // 786432
#define EPSF 1e-6f
#define LOG2E 1.4426950408889634f

// ---- workspace layout (float offsets) ----
#define QR_OFF 0                               // [B*C][H] query row sums
#define QC_OFF (QR_OFF + BC*HH)                // [B*C][W] query col sums
#define QS_OFF (QC_OFF + BC*WW)                // [B*C]    query totals
#define KR_OFF (QS_OFF + BC)                   // [B*C][H] key row sums
#define KC_OFF (KR_OFF + BC*HH)                // [B*C][W] key col sums
#define KS_OFF (KC_OFF + BC*WW)                // [B*C]    key totals
// per-(c0,plane) packed record (vb = c0*BC + plane), RECSZ floats, DE-INTERLEAVED:
//   [0:96)     m_r ×log2e    [96:192)  m_c ×log2e
//   [192:320)  n_r           [320:448) n_c
//   [448:832)  R4 [h][4]     [832:1344) C4 [w][4]
#define REC_OFF (KS_OFF + BC)                  // == 28800
#define RECSZ 1344
#define BMX_OFF (REC_OFF + CC*BC*RECSZ)        // [2048][4] per-block term maxes (k3 out)
#define BSX_OFF (BMX_OFF + CC*BC*4)            // [1536]    per-block smax (k4 out)
#define PZ_OFF (BSX_OFF + 1536)                // [NPLANE]  partial z (cg=1)
// total = PZ_OFF + NPLANE ≈ 14.3 MB

__device__ __forceinline__ float rcpf(float x) { return __builtin_amdgcn_rcpf(x); }
__device__ __forceinline__ float e2(float x) { return __builtin_amdgcn_exp2f(x); }

typedef _Float16 h2v __attribute__((ext_vector_type(2)));
__device__ __forceinline__ unsigned pkrtz_u(float a, float b) {
  return __builtin_bit_cast(unsigned, __builtin_amdgcn_cvt_pkrtz(a, b));
}
__device__ __forceinline__ unsigned pk_add(unsigned a, unsigned b) {
  unsigned d; asm("v_pk_add_f16 %0, %1, %2" : "=v"(d) : "v"(a), "v"(b)); return d;
}
__device__ __forceinline__ unsigned pk_mul(unsigned a, unsigned b) {
  unsigned d; asm("v_pk_mul_f16 %0, %1, %2" : "=v"(d) : "v"(a), "v"(b)); return d;
}
__device__ __forceinline__ unsigned pk_max(unsigned a, unsigned b) {
  unsigned d; asm("v_pk_max_f16 %0, %1, %2" : "=v"(d) : "v"(a), "v"(b)); return d;
}
__device__ __forceinline__ float dot2acc(unsigned u, float acc) {
#if __has_builtin(__builtin_amdgcn_fdot2)
  h2v a = __builtin_bit_cast(h2v, u);
  h2v one = {(_Float16)1.0f, (_Float16)1.0f};
  return __builtin_amdgcn_fdot2(a, one, acc, false);
#else
  float lo = (float)__builtin_bit_cast(_Float16, (unsigned short)(u & 0xffff));
  float hi = (float)__builtin_bit_cast(_Float16, (unsigned short)(u >> 16));
  return acc + lo + hi;
#endif
}
__device__ __forceinline__ float h2max_f(unsigned u) {
  float lo = (float)__builtin_bit_cast(_Float16, (unsigned short)(u & 0xffff));
  float hi = (float)__builtin_bit_cast(_Float16, (unsigned short)(u >> 16));
  return fmaxf(lo, hi);
}

__device__ __forceinline__ float blkmax4(float v) {
  __shared__ float sred[4];
  #pragma unroll
  for (int o = 32; o > 0; o >>= 1) v = fmaxf(v, __shfl_xor(v, o, 64));
  if ((threadIdx.x & 63) == 0) sred[threadIdx.x >> 6] = v;
  __syncthreads();
  float r = fmaxf(fmaxf(sred[0], sred[1]), fmaxf(sred[2], sred[3]));
  __syncthreads();
  return r;
}

// ---------------- K1: per-plane row/col/total sums (queries and keys) ----------------
__global__ __launch_bounds__(256) void k1_plane_sums(const float* __restrict__ q,
                                                     const float* __restrict__ k,
                                                     float* __restrict__ ws) {
  int pb = blockIdx.x;
  int plane = pb & (BC - 1);
  const float* src = (pb < BC ? q : k) + (size_t)plane * HW;
  float* rowO = ws + (pb < BC ? QR_OFF : KR_OFF) + plane * HH;
  float* colO = ws + (pb < BC ? QC_OFF : KC_OFF) + plane * WW;
  float* totO = ws + (pb < BC ? QS_OFF : KS_OFF) + plane;
  __shared__ float cp[4 * WW];
  __shared__ float rsh[HH];
  __shared__ float wtot[2];
  int tid = threadIdx.x;
  int u = tid >> 6, l = tid & 63;
  float csum0 = 0.f, csum1 = 0.f;
  #pragma unroll 4
  for (int r = 0; r < 24; ++r) {
    int h = u * 24 + r;
    float v0 = src[h * WW + l];
    float v1 = src[h * WW + l + 64];
    csum0 += v0; csum1 += v1;
    float rs = v0 + v1;
    #pragma unroll
    for (int o = 1; o < 64; o <<= 1) rs += __shfl_xor(rs, o, 64);
    if (l == 0) { rowO[h] = rs; rsh[h] = rs; }
  }
  cp[u * WW + l] = csum0;
  cp[u * WW + l + 64] = csum1;
  __syncthreads();
  if (tid < WW) colO[tid] = cp[tid] + cp[WW + tid] + cp[2 * WW + tid] + cp[3 * WW + tid];
  float tv = (tid < HH) ? rsh[tid] : 0.f;
  if (tid < 128) {
    #pragma unroll
    for (int o = 1; o < 64; o <<= 1) tv += __shfl_xor(tv, o, 64);
    if ((tid & 63) == 0) wtot[tid >> 6] = tv;
  }
  __syncthreads();
  if (tid == 0) *totO = wtot[0] + wtot[1];
}

// ---------------- K2: min-max-normalized vectors into de-interleaved record fields ----------------
__device__ __forceinline__ float k2_raw(const float* __restrict__ ws, int type, int c0, int i, int L) {
  int bc = i / L, x = i - bc * L;
  int b = bc >> 5;
  if (type == 0) return ws[QS_OFF + b * CC + c0] * ws[KR_OFF + bc * HH + x] + HH * EPSF;
  if (type == 1) return ws[QR_OFF + (b * CC + c0) * HH + x] * ws[KS_OFF + bc] + HH * EPSF;
  if (type == 2) return ws[QS_OFF + b * CC + c0] * ws[KC_OFF + bc * WW + x] + WW * EPSF;
  return ws[QC_OFF + (b * CC + c0) * WW + x] * ws[KS_OFF + bc] + WW * EPSF;
}

__global__ __launch_bounds__(256) void k2_vec_norm(float* __restrict__ ws) {
  int c0 = blockIdx.x >> 2, type = blockIdx.x & 3;
  int L = (type < 2) ? HH : WW;
  int N = BC * L;
  int tid = threadIdx.x;
  float mx = -FLT_MAX, mn = FLT_MAX;
  for (int i = tid; i < N; i += 256) {
    float v = k2_raw(ws, type, c0, i, L);
    mx = fmaxf(mx, v); mn = fminf(mn, v);
  }
  mx = blkmax4(mx);
  mn = -blkmax4(-mn);
  float scale = rcpf(mx - mn);
  float fold = (type < 2) ? LOG2E : 1.0f;
  int fieldbase = (type == 0) ? 0 : (type == 1) ? 96 : (type == 2) ? 192 : 320;
  for (int i = tid; i < N; i += 256) {
    int bc = i / L, x = i - bc * L;
    float v = k2_raw(ws, type, c0, i, L);
    ws[REC_OFF + (size_t)(c0 * BC + bc) * RECSZ + fieldbase + x] =
        (2.0f + (v - mn) * scale) * fold;
  }
}

// ---------------- K3: one block per (vb,t); e computed ONCE, fp16 LDS; packed reduce ----------------
#define EPH 136                        // halves per row (272B, 16B-aligned)
__global__ __launch_bounds__(256) void k3_rc(float* __restrict__ ws) {
  int g = blockIdx.x;                  // vb*4 + t
  int vb = g >> 2, t = g & 3;
  float* rec = ws + REC_OFF + (size_t)vb * RECSZ;
  int tid = threadIdx.x;
  int u = tid >> 6, l = tid & 63;
  __shared__ __align__(16) unsigned short eh[HH * EPH];   // 26112 B fp16 e
  __shared__ __align__(16) float mncp[512];               // m[0:96] n[96:224]; later cpart[4][128]
  __shared__ __align__(16) unsigned short rch[128];       // fp16 4096*rC
  __shared__ float wmx[3];
  const float* mv = rec + (t >> 1) * 96;
  const float* nv = rec + 192 + (t & 1) * 128;
  if (tid < 224) mncp[tid] = (tid < 96) ? mv[tid] : nv[tid - 96];
  __syncthreads();                                        // B1
  // ---- pass A: wave u owns rows 24u..24u+23; lane owns cols 2l,2l+1. e once. ----
  float n0 = mncp[96 + 2 * l], n1 = mncp[96 + 2 * l + 1];
  float cs0 = 0.f, cs1 = 0.f;
  #pragma unroll 6
  for (int r = 0; r < 24; ++r) {
    int h = u * 24 + r;
    float m = mncp[h];
    float e0 = e2(m * n0);
    float e1 = e2(m * n1);
    cs0 += e0; cs1 += e1;
    *(unsigned*)&eh[h * EPH + 2 * l] = pkrtz_u(e0, e1);
  }
  __syncthreads();                                        // B2 (mn reads done, eh complete)
  mncp[u * 128 + 2 * l] = cs0;
  mncp[u * 128 + 2 * l + 1] = cs1;
  __syncthreads();                                        // B3 (cpart ready)
  if (tid < 64) {                      // lane owns cols 2tid, 2tid+1
    int w0 = 2 * tid, w1 = w0 + 1;
    float rc0 = rcpf(mncp[w0] + mncp[128 + w0] + mncp[256 + w0] + mncp[384 + w0]);
    float rc1 = rcpf(mncp[w1] + mncp[128 + w1] + mncp[256 + w1] + mncp[384 + w1]);
    rec[832 + 4 * w0 + t] = rc0;
    rec[832 + 4 * w1 + t] = rc1;
    ((unsigned*)rch)[tid] = pkrtz_u(rc0 * 4096.f, rc1 * 4096.f);
  }
  __syncthreads();                                        // B4 (rch ready)
  // ---- pass B+C: lanes 0-191 own half-rows (row=tid>>1, hf=tid&1) ----
  float mx = 0.f;
  if (tid < 192) {
    int row = tid >> 1, hf = tid & 1;
    const uint4* ep = (const uint4*)&eh[row * EPH + hf * 64];
    float s = 0.f;
    #pragma unroll
    for (int j = 0; j < 8; ++j) {
      uint4 ev = ep[j];
      s = dot2acc(ev.x, s); s = dot2acc(ev.y, s);
      s = dot2acc(ev.z, s); s = dot2acc(ev.w, s);
    }
    s += __shfl_xor(s, 1, 64);         // partner has other w-half of same row
    float rr = rcpf(s);
    if (hf == 0) rec[448 + 4 * row + t] = rr;
    unsigned rr2 = pkrtz_u(rr * 4096.f, rr * 4096.f);
    unsigned mxu = 0;
    const uint4* cp2 = (const uint4*)&rch[hf * 64];
    #pragma unroll
    for (int j = 0; j < 8; ++j) {
      uint4 ev = ep[j];
      uint4 cv = cp2[j];
      mxu = pk_max(mxu, pk_mul(ev.x, pk_add(cv.x, rr2)));
      mxu = pk_max(mxu, pk_mul(ev.y, pk_add(cv.y, rr2)));
      mxu = pk_max(mxu, pk_mul(ev.z, pk_add(cv.z, rr2)));
      mxu = pk_max(mxu, pk_mul(ev.w, pk_add(cv.w, rr2)));
    }
    mx = h2max_f(mxu) * (1.0f / 4096.f);
    #pragma unroll
    for (int o = 1; o < 64; o <<= 1) mx = fmaxf(mx, __shfl_xor(mx, o, 64));
    if ((tid & 63) == 0) wmx[tid >> 6] = mx;
  }
  __syncthreads();                                        // B5
  if (tid == 0) ws[BMX_OFF + vb * 4 + t] = fmaxf(fmaxf(wmx[0], wmx[1]), wmx[2]);
}

// ---------------- K4: c-split ×2, ELEMS=4, all-LDS; partial z; pre-scaled R4/C4 ----------------
#define ELEMS 4
#define TILES 12                       // 256*ELEMS*TILES == HW
#define NCG 2
#define CG (CC/NCG)                    // 16
#define GRP 4
__global__ __launch_bounds__(256) void k4_score(const float* __restrict__ values,
                                                float* __restrict__ ws,
                                                float* __restrict__ out) {
  int bx = blockIdx.x;                 // (cb*TILES + tile)*2 + cg  -> 1536 blocks
  int cg = bx & 1, bxx = bx >> 1;
  int tile = bxx % TILES;
  int cb = bxx / TILES;
  int b = cb & 1, c0 = cb >> 1;
  int tid = threadIdx.x;
  int base = tile * 1024;              // 8 rows per block
  int w = tid & 127, r0 = tid >> 7;
  __shared__ __align__(16) float nS[GRP][256];    // [ch][ nr 0:128 | nc 128:256 ]
  __shared__ __align__(16) float c4S[GRP][512];   // [ch][ C4×im flat ]
  __shared__ __align__(16) float mrf[CG * 48];    // [ch][ m_r[8] | m_c[8] | r4×im[32] ]
  __shared__ float s44[4][4];
  const float* rec0 = ws + REC_OFF + (size_t)(c0 * BC + b * CC) * RECSZ;
  const float* recg = rec0 + (size_t)(cg * CG) * RECSZ;
  // --- prologue: BMX reduce + raw mrf stage (own 16 channels) + v loads ---
  float bm = ws[BMX_OFF + c0 * 256 + tid];
  #pragma unroll
  for (int o = 4; o <= 32; o <<= 1) bm = fmaxf(bm, __shfl_xor(bm, o, 64));
  if ((tid & 63) < 4) s44[tid >> 6][tid & 3] = bm;
  if (tid < 192) {                     // 16 ch × 12 float4
    int ch = tid / 12, f = tid - 12 * (tid / 12);
    const float* rsrc = recg + (size_t)ch * RECSZ;
    int soff = (f < 2) ? tile * 8 + 4 * f
             : (f < 4) ? 96 + tile * 8 + 4 * (f - 2)
                       : 448 + 32 * tile + 4 * (f - 4);
    *(float4*)&mrf[ch * 48 + f * 4] = *(const float4*)(rsrc + soff);
  }
  const float* vsrc0 = values + (size_t)(b * CC) * HW + base + tid;
  float vr[ELEMS];
  #pragma unroll
  for (int j = 0; j < ELEMS; ++j) vr[j] = vsrc0[(size_t)(cg * CG) * HW + 256 * j];
  __syncthreads();                     // B1: s44 + raw mrf visible
  float im0 = rcpf(fmaxf(fmaxf(s44[0][0], s44[1][0]), fmaxf(s44[2][0], s44[3][0])));
  float im1 = rcpf(fmaxf(fmaxf(s44[0][1], s44[1][1]), fmaxf(s44[2][1], s44[3][1])));
  float im2 = rcpf(fmaxf(fmaxf(s44[0][2], s44[1][2]), fmaxf(s44[2][2], s44[3][2])));
  float im3 = rcpf(fmaxf(fmaxf(s44[0][3], s44[1][3]), fmaxf(s44[2][3], s44[3][3])));
  // scale mrf r4 region in place (distinct entries per thread)
  for (int i = tid; i < CG * 32; i += 256) {
    int ch = i >> 5, kk = i & 31, tt = kk & 3;
    float sel = tt == 0 ? im0 : tt == 1 ? im1 : tt == 2 ? im2 : im3;
    mrf[ch * 48 + 16 + kk] *= sel;
  }
  // stage group 0 (c4 scaled)
  #pragma unroll
  for (int i = tid; i < GRP * 192; i += 256) {
    int chl = i / 192, rem = i - 192 * (i / 192);
    const float* rsrc = recg + (size_t)chl * RECSZ;
    if (rem < 64) {
      *(float4*)&nS[chl][4 * rem] = *(const float4*)(rsrc + 192 + 4 * rem);
    } else {
      float4 g4 = *(const float4*)(rsrc + 832 + 4 * (rem - 64));
      g4.x *= im0; g4.y *= im1; g4.z *= im2; g4.w *= im3;
      *(float4*)&c4S[chl][4 * (rem - 64)] = g4;
    }
  }
  __syncthreads();                     // B2: group 0 + scaled mrf visible
  float U[ELEMS] = {0.f, 0.f, 0.f, 0.f};
  float smaxl = 0.f;
  for (int ci = 0; ci < CG; ++ci) {
    if ((ci & (GRP - 1)) == 0 && ci) { // re-stage group ci/GRP
      __syncthreads();
      #pragma unroll
      for (int i = tid; i < GRP * 192; i += 256) {
        int chl = i / 192, rem = i - 192 * (i / 192);
        const float* rsrc = recg + (size_t)(ci + chl) * RECSZ;
        if (rem < 64) {
          *(float4*)&nS[chl][4 * rem] = *(const float4*)(rsrc + 192 + 4 * rem);
        } else {
          float4 g4 = *(const float4*)(rsrc + 832 + 4 * (rem - 64));
          g4.x *= im0; g4.y *= im1; g4.z *= im2; g4.w *= im3;
          *(float4*)&c4S[chl][4 * (rem - 64)] = g4;
        }
      }
      __syncthreads();
    }
    float nv[ELEMS];
    if (ci + 1 < CG) {                 // prefetch next channel's values
      #pragma unroll
      for (int j = 0; j < ELEMS; ++j)
        nv[j] = vsrc0[(size_t)(cg * CG + ci + 1) * HW + 256 * j];
    }
    int cl = ci & (GRP - 1);
    float nr = nS[cl][w], nc = nS[cl][128 + w];
    float4 c4 = *(const float4*)&c4S[cl][4 * w];
    const float* mc = &mrf[ci * 48];
    #pragma unroll
    for (int j = 0; j < ELEMS; ++j) {
      int r = r0 + 2 * j;
      float mR = mc[r], mC = mc[8 + r];
      float4 r4 = *(const float4*)&mc[16 + 4 * r];
      float sc = e2(mR * nr) * (r4.x + c4.x) + e2(mR * nc) * (r4.y + c4.y)
               + e2(mC * nr) * (r4.z + c4.z) + e2(mC * nc) * (r4.w + c4.w);
      smaxl = fmaxf(smaxl, sc);
      U[j] += sc * vr[j];
    }
    if (ci + 1 < CG) {
      #pragma unroll
      for (int j = 0; j < ELEMS; ++j) vr[j] = nv[j];
    }
  }
  float* zt = (cg == 0 ? out : ws + PZ_OFF) + (size_t)(b * CC + c0) * HW + base + tid;
  #pragma unroll
  for (int j = 0; j < ELEMS; ++j) zt[256 * j] = U[j];
  smaxl = blkmax4(smaxl);
  if (tid == 0) ws[BSX_OFF + bx] = smaxl;
}

// ---------------- K5: z combine+scale (512 blocks) + score recompute c0=31 (128 blocks) ----------------
#define K5_ZB (BC * 8)                 // 512
__global__ __launch_bounds__(256) void k5_final(float* __restrict__ out,
                                                const float* __restrict__ ws) {
  int bx = blockIdx.x;
  int tid = threadIdx.x;
  if (bx < K5_ZB) {
    int p = bx >> 3, sub = bx & 7;     // p = b*CC + c0 z-plane
    int c0 = p & (CC - 1);
    __shared__ float sm;
    if (tid < 64) {
      float a = (tid < 48) ? ws[BSX_OFF + c0 * 48 + tid] : 0.f;
      #pragma unroll
      for (int o = 1; o < 64; o <<= 1) a = fmaxf(a, __shfl_xor(a, o, 64));
      if (tid == 0) sm = a;
    }
    __syncthreads();
    float ism = rcpf(sm);
    const float* pz = ws + PZ_OFF;
    int off = p * HW + sub * 1536 + tid;
    #pragma unroll
    for (int j = 0; j < 6; ++j) {
      int i = off + 256 * j;
      out[i] = (out[i] + pz[i]) * ism;
    }
  } else {
    int sp = bx - K5_ZB;               // 128 blocks: plane = sp>>1, half = sp&1
    int plane = sp >> 1, half = sp & 1;
    const float* rec = ws + REC_OFF + (size_t)((CC - 1) * BC + plane) * RECSZ;
    __shared__ __align__(16) float R[RECSZ];
    __shared__ float s44[4][4];
    __shared__ float sm;
    for (int i = tid; i < RECSZ / 4; i += 256) ((float4*)R)[i] = ((const float4*)rec)[i];
    float bm = ws[BMX_OFF + (CC - 1) * 256 + tid];
    #pragma unroll
    for (int o = 4; o <= 32; o <<= 1) bm = fmaxf(bm, __shfl_xor(bm, o, 64));
    if ((tid & 63) < 4) s44[tid >> 6][tid & 3] = bm;
    if (tid < 64) {
      float a = (tid < 48) ? ws[BSX_OFF + (CC - 1) * 48 + tid] : 0.f;
      #pragma unroll
      for (int o = 1; o < 64; o <<= 1) a = fmaxf(a, __shfl_xor(a, o, 64));
      if (tid == 0) sm = a;
    }
    __syncthreads();
    float im0 = rcpf(fmaxf(fmaxf(s44[0][0], s44[1][0]), fmaxf(s44[2][0], s44[3][0])));
    float im1 = rcpf(fmaxf(fmaxf(s44[0][1], s44[1][1]), fmaxf(s44[2][1], s44[3][1])));
    float im2 = rcpf(fmaxf(fmaxf(s44[0][2], s44[1][2]), fmaxf(s44[2][2], s44[3][2])));
    float im3 = rcpf(fmaxf(fmaxf(s44[0][3], s44[1][3]), fmaxf(s44[2][3], s44[3][3])));
    float isml = rcpf(sm);
    float* sout = out + (size_t)NPLANE + (size_t)plane * HW + half * 6144;
    #pragma unroll 4
    for (int e = tid; e < 6144; e += 256) {
      int idx = half * 6144 + e;
      int h = idx >> 7, ww = idx & 127;
      float mR = R[h], mC = R[96 + h];
      float nr = R[192 + ww], nc = R[320 + ww];
      float4 r4 = *(const float4*)&R[448 + 4 * h];
      float4 c4 = *(const float4*)&R[832 + 4 * ww];
      float A0 = c4.x * im0, A1 = c4.y * im1, A2 = c4.z * im2, A3 = c4.w * im3;
      float sc = e2(mR * nr) * fmaf(r4.x, im0, A0) + e2(mR * nc) * fmaf(r4.y, im1, A1)
               + e2(mC * nr) * fmaf(r4.z, im2, A2) + e2(mC * nc) * fmaf(r4.w, im3, A3);
      sout[e] = sc * isml;
    }
  }
}

extern "C" void kernel_launch(void* const* d_in, const int* in_sizes, int n_in,
                              void* d_out, int out_size, void* d_ws, size_t ws_size,
                              hipStream_t stream) {
  const float* q = (const float*)d_in[0];
  const float* k = (const float*)d_in[1];
  const float* v = (const float*)d_in[2];
  float* out = (float*)d_out;
  float* ws = (float*)d_ws;
  k1_plane_sums<<<2 * BC, 256, 0, stream>>>(q, k, ws);
  k2_vec_norm<<<CC * 4, 256, 0, stream>>>(ws);
  k3_rc<<<CC * BC * 4, 256, 0, stream>>>(ws);
  k4_score<<<CC * BB * TILES * NCG, 256, 0, stream>>>(v, ws, out);
  k5_final<<<K5_ZB + 128, 256, 0, stream>>>(out, ws);
}